// Round 24
// baseline (349.985 us; speedup 1.0000x reference)
//
#include <hip/hip_runtime.h>
#include <hip/hip_bf16.h>
#include <math.h>

#define NQd 100
#define BSd 8
#define NPTd 17
#define DIMd 256
#define NHd 8
#define DHd 32
#define DFFd 1024
#define NTOK (NQd*BSd*NPTd)        // 13600
#define LENIN 11253
#define MTOK (BSd*LENIN)           // 90024

typedef __attribute__((ext_vector_type(8))) short bf16x8;
typedef __attribute__((ext_vector_type(4))) short bf16x4s;
typedef __attribute__((ext_vector_type(4))) float f32x4;

__device__ inline short f2bs(float f) {
    __hip_bfloat16 h = __float2bfloat16(f);
    return *reinterpret_cast<short*>(&h);
}
__device__ inline float bs2f(short s) {
    return __uint_as_float(((unsigned)(unsigned short)s) << 16);
}

// ---------------------------------------------------------------------------
// 64x64-tile GEMM, machine-fill workhorse. 256 thr, 4 waves 2x2, per-wave
// 32x32 (acc[2][2]). Grid (N/64) x ceil(M/64).
// AMAP: 0 = A bf16 identity; 1 = A fp32 identity; 2 = A fp32 + add identity
// (QK: tgt+qpos); 3 = A fp32, y-order row map (phase-2 input from X).
// Row maps proven in rounds 10-13; rounding at staging == old gather+re-read.
// ---------------------------------------------------------------------------
template<int AMAP, bool OUT_BF16, bool RELU>
__global__ __launch_bounds__(256)
void gemm64(const void* __restrict__ Av, const float* __restrict__ Aadd,
            const __hip_bfloat16* __restrict__ W, const float* __restrict__ bias,
            void* __restrict__ Cv, int M, int K, int ldc, int col0) {
    __shared__ __hip_bfloat16 LA[2][4][65][8];
    __shared__ __hip_bfloat16 LW[2][4][65][8];
    const int tid = threadIdx.x;
    const int lane = tid & 63, wave = tid >> 6;
    const int wr = wave >> 1, wc = wave & 1;
    const int m0 = blockIdx.y * 64, n0 = blockIdx.x * 64;
    const int l15 = lane & 15, lg = lane >> 4;
    const int srow = tid >> 2, koct = tid & 3;
    const int gm = m0 + srow;
    const bool okA = gm < M;
    int src = okA ? gm : 0;
    if (AMAP == 3) src = (src % 100) * 136 + src / 100;
    const __hip_bfloat16* pAb = (const __hip_bfloat16*)Av + (size_t)src * K + koct * 8;
    const float* pAf = (const float*)Av + (size_t)src * K + koct * 8;
    const float* pDf = (AMAP == 2) ? (Aadd + (size_t)src * K + koct * 8) : nullptr;
    const __hip_bfloat16* pW = W + (size_t)(n0 + srow) * K + koct * 8;

    bf16x8 aR, wR;
    float4 f0R, f1R, d0R, d1R;
    auto load_tile = [&](int k0) {
        if (AMAP == 0) {
            aR = okA ? *(const bf16x8*)(pAb + k0) : (bf16x8){0, 0, 0, 0, 0, 0, 0, 0};
        } else {
            f0R = okA ? *(const float4*)(pAf + k0)     : make_float4(0.f, 0.f, 0.f, 0.f);
            f1R = okA ? *(const float4*)(pAf + k0 + 4) : make_float4(0.f, 0.f, 0.f, 0.f);
            if (AMAP == 2) {
                d0R = okA ? *(const float4*)(pDf + k0)     : make_float4(0.f, 0.f, 0.f, 0.f);
                d1R = okA ? *(const float4*)(pDf + k0 + 4) : make_float4(0.f, 0.f, 0.f, 0.f);
            }
        }
        wR = *(const bf16x8*)(pW + k0);
    };
    auto write_tile = [&](int buf) {
        bf16x8 v;
        if (AMAP == 0) {
            v = aR;
        } else {
            float4 f0 = f0R, f1 = f1R;
            if (AMAP == 2) {
                f0.x += d0R.x; f0.y += d0R.y; f0.z += d0R.z; f0.w += d0R.w;
                f1.x += d1R.x; f1.y += d1R.y; f1.z += d1R.z; f1.w += d1R.w;
            }
            v = (bf16x8){f2bs(f0.x), f2bs(f0.y), f2bs(f0.z), f2bs(f0.w),
                         f2bs(f1.x), f2bs(f1.y), f2bs(f1.z), f2bs(f1.w)};
        }
        *(bf16x8*)&LA[buf][koct][srow][0] = v;
        *(bf16x8*)&LW[buf][koct][srow][0] = wR;
    };

    f32x4 acc[2][2];
#pragma unroll
    for (int i = 0; i < 2; ++i)
#pragma unroll
        for (int j = 0; j < 2; ++j) acc[i][j] = (f32x4){0.f, 0.f, 0.f, 0.f};

    const int NT = K >> 5;
    load_tile(0);
    write_tile(0);
    __syncthreads();
    for (int t = 0; t < NT; ++t) {
        const int cur = t & 1;
        if (t + 1 < NT) load_tile((t + 1) * 32);
        bf16x8 af[2], bfr[2];
#pragma unroll
        for (int f = 0; f < 2; ++f) {
            af[f]  = *(const bf16x8*)&LA[cur][lg][wr * 32 + f * 16 + l15][0];
            bfr[f] = *(const bf16x8*)&LW[cur][lg][wc * 32 + f * 16 + l15][0];
        }
#pragma unroll
        for (int fm = 0; fm < 2; ++fm)
#pragma unroll
            for (int fn = 0; fn < 2; ++fn)
                acc[fm][fn] = __builtin_amdgcn_mfma_f32_16x16x32_bf16(af[fm], bfr[fn], acc[fm][fn], 0, 0, 0);
        if (t + 1 < NT) write_tile(cur ^ 1);
        __syncthreads();
    }

#pragma unroll
    for (int fm = 0; fm < 2; ++fm) {
        const int row = m0 + wr * 32 + fm * 16 + lg * 4;
#pragma unroll
        for (int fn = 0; fn < 2; ++fn) {
            const int coln = n0 + wc * 32 + fn * 16 + l15;
            const float bsv = bias[coln];
#pragma unroll
            for (int r = 0; r < 4; ++r) {
                const int gr = row + r;
                if (gr >= M) continue;
                float v = acc[fm][fn][r] + bsv;
                if (RELU) v = fmaxf(v, 0.f);
                if (OUT_BF16)
                    ((__hip_bfloat16*)Cv)[(size_t)gr * ldc + col0 + coln] = __float2bfloat16(v);
                else
                    ((float*)Cv)[(size_t)gr * ldc + col0 + coln] = v;
            }
        }
    }
}

// ---------------------------------------------------------------------------
// gemm64qa: fused deform-gather + offsets/attn-weights projection.
// A = X[r] + qpos[r] with deform-order row map (t -> r), W = packed
// [w_off (256) | w_aw (128)] contiguous, N = 384. Split epilogue:
// cols <256 -> Coff (fp32, ld 256); cols >=256 -> Caw (fp32, ld 128).
// ---------------------------------------------------------------------------
__global__ __launch_bounds__(256)
void gemm64qa(const float* __restrict__ X, const float* __restrict__ qpos,
              const __hip_bfloat16* __restrict__ W,
              const float* __restrict__ boff, const float* __restrict__ baw,
              float* __restrict__ Coff, float* __restrict__ Caw, int M, int K) {
    __shared__ __hip_bfloat16 LA[2][4][65][8];
    __shared__ __hip_bfloat16 LW[2][4][65][8];
    const int tid = threadIdx.x;
    const int lane = tid & 63, wave = tid >> 6;
    const int wr = wave >> 1, wc = wave & 1;
    const int m0 = blockIdx.y * 64, n0 = blockIdx.x * 64;
    const int l15 = lane & 15, lg = lane >> 4;
    const int srow = tid >> 2, koct = tid & 3;
    const int gm = m0 + srow;
    const bool okA = gm < M;
    int t_ = okA ? gm : 0;
    {
        int b = t_ / 1700, jj = t_ % 1700;
        int qq = jj / 17, p = jj % 17;
        t_ = qq * 136 + b * 17 + p;
    }
    const float* pAf = X + (size_t)t_ * K + koct * 8;
    const float* pDf = qpos + (size_t)t_ * K + koct * 8;
    const __hip_bfloat16* pW = W + (size_t)(n0 + srow) * K + koct * 8;

    bf16x8 wR;
    float4 f0R, f1R, d0R, d1R;
    auto load_tile = [&](int k0) {
        f0R = okA ? *(const float4*)(pAf + k0)     : make_float4(0.f, 0.f, 0.f, 0.f);
        f1R = okA ? *(const float4*)(pAf + k0 + 4) : make_float4(0.f, 0.f, 0.f, 0.f);
        d0R = okA ? *(const float4*)(pDf + k0)     : make_float4(0.f, 0.f, 0.f, 0.f);
        d1R = okA ? *(const float4*)(pDf + k0 + 4) : make_float4(0.f, 0.f, 0.f, 0.f);
        wR = *(const bf16x8*)(pW + k0);
    };
    auto write_tile = [&](int buf) {
        *(bf16x8*)&LA[buf][koct][srow][0] =
            (bf16x8){f2bs(f0R.x + d0R.x), f2bs(f0R.y + d0R.y),
                     f2bs(f0R.z + d0R.z), f2bs(f0R.w + d0R.w),
                     f2bs(f1R.x + d1R.x), f2bs(f1R.y + d1R.y),
                     f2bs(f1R.z + d1R.z), f2bs(f1R.w + d1R.w)};
        *(bf16x8*)&LW[buf][koct][srow][0] = wR;
    };

    f32x4 acc[2][2];
#pragma unroll
    for (int i = 0; i < 2; ++i)
#pragma unroll
        for (int j = 0; j < 2; ++j) acc[i][j] = (f32x4){0.f, 0.f, 0.f, 0.f};

    const int NT = K >> 5;
    load_tile(0);
    write_tile(0);
    __syncthreads();
    for (int t = 0; t < NT; ++t) {
        const int cur = t & 1;
        if (t + 1 < NT) load_tile((t + 1) * 32);
        bf16x8 af[2], bfr[2];
#pragma unroll
        for (int f = 0; f < 2; ++f) {
            af[f]  = *(const bf16x8*)&LA[cur][lg][wr * 32 + f * 16 + l15][0];
            bfr[f] = *(const bf16x8*)&LW[cur][lg][wc * 32 + f * 16 + l15][0];
        }
#pragma unroll
        for (int fm = 0; fm < 2; ++fm)
#pragma unroll
            for (int fn = 0; fn < 2; ++fn)
                acc[fm][fn] = __builtin_amdgcn_mfma_f32_16x16x32_bf16(af[fm], bfr[fn], acc[fm][fn], 0, 0, 0);
        if (t + 1 < NT) write_tile(cur ^ 1);
        __syncthreads();
    }

#pragma unroll
    for (int fm = 0; fm < 2; ++fm) {
        const int row = m0 + wr * 32 + fm * 16 + lg * 4;
#pragma unroll
        for (int fn = 0; fn < 2; ++fn) {
            const int coln = n0 + wc * 32 + fn * 16 + l15;
#pragma unroll
            for (int r = 0; r < 4; ++r) {
                const int gr = row + r;
                if (gr >= M) continue;
                if (coln < 256) {
                    Coff[(size_t)gr * 256 + coln] = acc[fm][fn][r] + boff[coln];
                } else {
                    Caw[(size_t)gr * 128 + (coln - 256)] = acc[fm][fn][r] + baw[coln - 256];
                }
            }
        }
    }
}

// ---------------------------------------------------------------------------
// gemm64x: value projection (M=90024, N=256, fp32 A -> bf16 C).
// 5628 blocks + m204 bijective XCD-chunked swizzle (FETCH 45.6 MB measured).
// ---------------------------------------------------------------------------
__global__ __launch_bounds__(256)
void gemm64x(const float* __restrict__ Av, const __hip_bfloat16* __restrict__ W,
             const float* __restrict__ bias, __hip_bfloat16* __restrict__ Cv,
             int M, int K, int ldc) {
    const int nwg = gridDim.x;
    const int orig = blockIdx.x;
    const int xcd = orig & 7, loc = orig >> 3;
    const int q = nwg >> 3, r = nwg & 7;
    const int swz = (xcd < r ? xcd * (q + 1) : r * (q + 1) + (xcd - r) * q) + loc;
    const int m0 = (swz >> 2) * 64, n0 = (swz & 3) * 64;

    __shared__ __hip_bfloat16 LA[2][4][65][8];
    __shared__ __hip_bfloat16 LW[2][4][65][8];
    const int tid = threadIdx.x;
    const int lane = tid & 63, wave = tid >> 6;
    const int wr = wave >> 1, wc = wave & 1;
    const int l15 = lane & 15, lg = lane >> 4;
    const int srow = tid >> 2, koct = tid & 3;
    const int gm = m0 + srow;
    const bool okA = gm < M;
    const float* pAf = Av + (size_t)(okA ? gm : 0) * K + koct * 8;
    const __hip_bfloat16* pW = W + (size_t)(n0 + srow) * K + koct * 8;

    bf16x8 wR;
    float4 f0R, f1R;
    auto load_tile = [&](int k0) {
        f0R = okA ? *(const float4*)(pAf + k0)     : make_float4(0.f, 0.f, 0.f, 0.f);
        f1R = okA ? *(const float4*)(pAf + k0 + 4) : make_float4(0.f, 0.f, 0.f, 0.f);
        wR = *(const bf16x8*)(pW + k0);
    };
    auto write_tile = [&](int buf) {
        *(bf16x8*)&LA[buf][koct][srow][0] =
            (bf16x8){f2bs(f0R.x), f2bs(f0R.y), f2bs(f0R.z), f2bs(f0R.w),
                     f2bs(f1R.x), f2bs(f1R.y), f2bs(f1R.z), f2bs(f1R.w)};
        *(bf16x8*)&LW[buf][koct][srow][0] = wR;
    };

    f32x4 acc[2][2];
#pragma unroll
    for (int i = 0; i < 2; ++i)
#pragma unroll
        for (int j = 0; j < 2; ++j) acc[i][j] = (f32x4){0.f, 0.f, 0.f, 0.f};

    const int NT = K >> 5;
    load_tile(0);
    write_tile(0);
    __syncthreads();
    for (int t = 0; t < NT; ++t) {
        const int cur = t & 1;
        if (t + 1 < NT) load_tile((t + 1) * 32);
        bf16x8 af[2], bfr[2];
#pragma unroll
        for (int f = 0; f < 2; ++f) {
            af[f]  = *(const bf16x8*)&LA[cur][lg][wr * 32 + f * 16 + l15][0];
            bfr[f] = *(const bf16x8*)&LW[cur][lg][wc * 32 + f * 16 + l15][0];
        }
#pragma unroll
        for (int fm = 0; fm < 2; ++fm)
#pragma unroll
            for (int fn = 0; fn < 2; ++fn)
                acc[fm][fn] = __builtin_amdgcn_mfma_f32_16x16x32_bf16(af[fm], bfr[fn], acc[fm][fn], 0, 0, 0);
        if (t + 1 < NT) write_tile(cur ^ 1);
        __syncthreads();
    }

#pragma unroll
    for (int fm = 0; fm < 2; ++fm) {
        const int row = m0 + wr * 32 + fm * 16 + lg * 4;
#pragma unroll
        for (int fn = 0; fn < 2; ++fn) {
            const int coln = n0 + wc * 32 + fn * 16 + l15;
            const float bsv = bias[coln];
#pragma unroll
            for (int r = 0; r < 4; ++r) {
                const int gr = row + r;
                if (gr >= M) continue;
                Cv[(size_t)gr * ldc + coln] = __float2bfloat16(acc[fm][fn][r] + bsv);
            }
        }
    }
}

// ---------------------------------------------------------------------------
// Fused weight conversion fp32 -> bf16 into one packed buffer.
// ---------------------------------------------------------------------------
__global__ void cvt_weights(const float* w0, const float* w1, const float* w2,
                            const float* w3, const float* w4, const float* w5,
                            const float* w6, const float* w7, const float* w8,
                            const float* w9, __hip_bfloat16* dst) {
    int idx = blockIdx.x * 256 + threadIdx.x;
    float v;
    if      (idx <  196608) v = w0[idx];
    else if (idx <  262144) v = w1[idx -  196608];
    else if (idx <  458752) v = w2[idx -  262144];
    else if (idx <  524288) v = w3[idx -  458752];
    else if (idx <  589824) v = w4[idx -  524288];
    else if (idx <  622592) v = w5[idx -  589824];
    else if (idx <  688128) v = w6[idx -  622592];
    else if (idx <  753664) v = w7[idx -  688128];
    else if (idx < 1015808) v = w8[idx -  753664];
    else                    v = w9[idx - 1015808];
    dst[idx] = __float2bfloat16(v);
}

// ---------------------------------------------------------------------------
// MHA S=17 (group attention). qkv BF16 rows t*768 (Q|K|V). block=(group, head)
// ---------------------------------------------------------------------------
__global__ void attn17(const __hip_bfloat16* __restrict__ qkv, __hip_bfloat16* __restrict__ out) {
    const int g = blockIdx.x, h = blockIdx.y;
    __shared__ float q[17][32], k[17][32], v[17][32], s[17][18];
    const int tid = threadIdx.x;  // 256
    for (int idx = tid; idx < 17 * 32; idx += 256) {
        int i = idx >> 5, d = idx & 31;
        size_t row = (size_t)(g * 17 + i) * 768 + h * 32 + d;
        q[i][d] = bs2f(*(const short*)&qkv[row]);
        k[i][d] = bs2f(*(const short*)&qkv[row + 256]);
        v[i][d] = bs2f(*(const short*)&qkv[row + 512]);
    }
    __syncthreads();
    for (int idx = tid; idx < 17 * 17; idx += 256) {
        int i = idx / 17, j = idx % 17;
        float acc = 0.f;
#pragma unroll
        for (int d = 0; d < 32; ++d) acc += q[i][d] * k[j][d];
        s[i][j] = acc * 0.17677669529663688f;
    }
    __syncthreads();
    if (tid < 17) {
        float m = -1e30f;
        for (int j = 0; j < 17; ++j) m = fmaxf(m, s[tid][j]);
        float sum = 0.f;
        for (int j = 0; j < 17; ++j) { float e = __expf(s[tid][j] - m); s[tid][j] = e; sum += e; }
        float inv = 1.f / sum;
        for (int j = 0; j < 17; ++j) s[tid][j] *= inv;
    }
    __syncthreads();
    for (int idx = tid; idx < 17 * 32; idx += 256) {
        int i = idx >> 5, d = idx & 31;
        float acc = 0.f;
        for (int j = 0; j < 17; ++j) acc += s[i][j] * v[j][d];
        out[(size_t)(g * 17 + i) * 256 + h * 32 + d] = __float2bfloat16(acc);
    }
}

// ---------------------------------------------------------------------------
// MHA S=100 v2: MFMA flash per (group, head). 128 thr = 2 waves. qkv BF16.
// ---------------------------------------------------------------------------
__global__ __launch_bounds__(128)
void attn100(const __hip_bfloat16* __restrict__ qkv, __hip_bfloat16* __restrict__ out) {
    const int g = blockIdx.x, h = blockIdx.y;
    __shared__ __hip_bfloat16 Vt[32][136];
    __shared__ __hip_bfloat16 Pl[2][16][136];
    const int tid = threadIdx.x;
    const int wave = tid >> 6, lane = tid & 63;
    const int l15 = lane & 15, lg = lane >> 4;

    for (int idx = tid; idx < 3200; idx += 128) {
        int j = idx >> 5, d = idx & 31;
        Vt[d][j] = qkv[(size_t)(g * 100 + j) * 768 + 512 + h * 32 + d];
    }
    for (int idx = tid; idx < 32 * 28; idx += 128) {
        int d = idx & 31, jz = 100 + (idx >> 5);
        Vt[d][jz] = __float2bfloat16(0.f);
    }
    __syncthreads();

    const int rt0 = wave ? 4 : 0, rt1 = wave ? 7 : 4;
    for (int rt = rt0; rt < rt1; ++rt) {
        const int rowbase = rt * 16;
        int qr = rowbase + l15; if (qr > 99) qr = 99;
        bf16x8 aq = *(const bf16x8*)(qkv + (size_t)(g * 100 + qr) * 768 + h * 32 + lg * 8);
        f32x4 s[7];
#pragma unroll
        for (int jt = 0; jt < 7; ++jt) {
            int jr = jt * 16 + l15; if (jr > 99) jr = 99;
            bf16x8 bk = *(const bf16x8*)(qkv + (size_t)(g * 100 + jr) * 768 + 256 + h * 32 + lg * 8);
            s[jt] = __builtin_amdgcn_mfma_f32_16x16x32_bf16(aq, bk, (f32x4){0.f, 0.f, 0.f, 0.f}, 0, 0, 0);
        }
        float mr[4] = {-1e30f, -1e30f, -1e30f, -1e30f};
#pragma unroll
        for (int jt = 0; jt < 7; ++jt) {
            const bool valid = (jt * 16 + l15) < 100;
#pragma unroll
            for (int r = 0; r < 4; ++r) {
                float v = valid ? s[jt][r] * 0.17677669529663688f : -1e30f;
                s[jt][r] = v;
                mr[r] = fmaxf(mr[r], v);
            }
        }
#pragma unroll
        for (int r = 0; r < 4; ++r) {
            mr[r] = fmaxf(mr[r], __shfl_xor(mr[r], 1));
            mr[r] = fmaxf(mr[r], __shfl_xor(mr[r], 2));
            mr[r] = fmaxf(mr[r], __shfl_xor(mr[r], 4));
            mr[r] = fmaxf(mr[r], __shfl_xor(mr[r], 8));
        }
        float lr[4] = {0.f, 0.f, 0.f, 0.f};
#pragma unroll
        for (int jt = 0; jt < 7; ++jt)
#pragma unroll
            for (int r = 0; r < 4; ++r) {
                float e = __expf(s[jt][r] - mr[r]);
                s[jt][r] = e;
                lr[r] += e;
            }
#pragma unroll
        for (int r = 0; r < 4; ++r) {
            lr[r] += __shfl_xor(lr[r], 1);
            lr[r] += __shfl_xor(lr[r], 2);
            lr[r] += __shfl_xor(lr[r], 4);
            lr[r] += __shfl_xor(lr[r], 8);
        }
#pragma unroll
        for (int jt = 0; jt < 7; ++jt)
#pragma unroll
            for (int r = 0; r < 4; ++r)
                Pl[wave][lg * 4 + r][jt * 16 + l15] = __float2bfloat16(s[jt][r]);
#pragma unroll
        for (int r = 0; r < 4; ++r)
            Pl[wave][lg * 4 + r][112 + l15] = __float2bfloat16(0.f);

        f32x4 o0 = (f32x4){0.f, 0.f, 0.f, 0.f};
        f32x4 o1 = (f32x4){0.f, 0.f, 0.f, 0.f};
#pragma unroll
        for (int c = 0; c < 4; ++c) {
            bf16x8 pa = *(const bf16x8*)&Pl[wave][l15][c * 32 + lg * 8];
            bf16x8 v0 = *(const bf16x8*)&Vt[l15][c * 32 + lg * 8];
            bf16x8 v1 = *(const bf16x8*)&Vt[16 + l15][c * 32 + lg * 8];
            o0 = __builtin_amdgcn_mfma_f32_16x16x32_bf16(pa, v0, o0, 0, 0, 0);
            o1 = __builtin_amdgcn_mfma_f32_16x16x32_bf16(pa, v1, o1, 0, 0, 0);
        }
#pragma unroll
        for (int r = 0; r < 4; ++r) {
            int row = rowbase + lg * 4 + r;
            if (row < 100) {
                float inv = 1.f / lr[r];
                __hip_bfloat16* op = out + (size_t)(g * 100 + row) * 256 + h * 32;
                op[l15]      = __float2bfloat16(o0[r] * inv);
                op[16 + l15] = __float2bfloat16(o1[r] * inv);
            }
        }
    }
}

// ---------------------------------------------------------------------------
// Deformable sampling: bf16 value input. block = 4 tokens, 256 threads.
// ---------------------------------------------------------------------------
#define TPB 4
__global__ __launch_bounds__(256)
void deform_sample(const __hip_bfloat16* __restrict__ value, const float* __restrict__ off,
                   const float* __restrict__ aw, const float* __restrict__ ref,
                   __hip_bfloat16* __restrict__ out) {
    const int t0 = blockIdx.x * TPB;
    const int tid = threadIdx.x;
    __shared__ float raw[TPB][128];
    __shared__ float wgt[TPB][128];
    __shared__ int   cidx[TPB][128][4];
    __shared__ float cw[TPB][128][4];

    for (int idx = tid; idx < TPB * 128; idx += 256) {
        int tk = idx >> 7, i = idx & 127;
        raw[tk][i] = aw[(size_t)(t0 + tk) * 128 + i];
    }
    __syncthreads();
    if (tid < TPB * 8) {
        int tk = tid >> 3, h = tid & 7;
        float m = -1e30f;
        for (int i = 0; i < 16; ++i) m = fmaxf(m, raw[tk][h * 16 + i]);
        float sum = 0.f;
        float e[16];
        for (int i = 0; i < 16; ++i) { e[i] = __expf(raw[tk][h * 16 + i] - m); sum += e[i]; }
        float inv = 1.f / sum;
        for (int i = 0; i < 16; ++i) wgt[tk][h * 16 + i] = e[i] * inv;
    }
    __syncthreads();

    const int Hs[4] = {92, 46, 23, 12};
    const int Sts[4] = {0, 8464, 10580, 11109};
    for (int s = tid; s < TPB * 128; s += 256) {
        int tk = s >> 7, sid = s & 127;
        int t = t0 + tk;
        int b = t / 1700, jj = t % 1700;
        int q = jj / 17, p = jj % 17;
        int l = (sid >> 2) & 3;
        int HW = Hs[l];
        float HWf = (float)HW;
        const float* refp = ref + (size_t)((q * 8 + b) * 17 + p) * 8;
        float rx = refp[l * 2], ry = refp[l * 2 + 1];
        float ox = off[(size_t)t * 256 + sid * 2];
        float oy = off[(size_t)t * 256 + sid * 2 + 1];
        float x = (rx + ox / HWf) * HWf - 0.5f;
        float y = (ry + oy / HWf) * HWf - 0.5f;
        float x0f = floorf(x), y0f = floorf(y);
        float wx = x - x0f, wy = y - y0f;
        int xi = (int)x0f, yi = (int)y0f;
        float wg = wgt[tk][sid];
#pragma unroll
        for (int c = 0; c < 4; ++c) {
            int cy = c >> 1, cx = c & 1;
            int yy = yi + cy, xx = xi + cx;
            bool ok = (xx >= 0) && (xx < HW) && (yy >= 0) && (yy < HW);
            int yc = min(max(yy, 0), HW - 1);
            int xc = min(max(xx, 0), HW - 1);
            cidx[tk][sid][c] = Sts[l] + yc * HW + xc;
            float w = (cy ? wy : 1.f - wy) * (cx ? wx : 1.f - wx);
            cw[tk][sid][c] = ok ? wg * w : 0.f;
        }
    }
    __syncthreads();

    const int tk = tid >> 6, lane = tid & 63;
    const int h = lane >> 3, d4 = (lane & 7) * 4;
    const int t = t0 + tk;
    const int b = t / 1700;
    const __hip_bfloat16* vb = value + (size_t)b * LENIN * 256 + h * 32 + d4;
    float4 acc = make_float4(0.f, 0.f, 0.f, 0.f);
    for (int s16 = 0; s16 < 16; ++s16) {
        int sid = h * 16 + s16;
#pragma unroll
        for (int c = 0; c < 4; ++c) {
            int idx = cidx[tk][sid][c];
            float w = cw[tk][sid][c];
            bf16x4s v = *(const bf16x4s*)(vb + (size_t)idx * 256);
            acc.x += w * bs2f(v.x); acc.y += w * bs2f(v.y);
            acc.z += w * bs2f(v.z); acc.w += w * bs2f(v.w);
        }
    }
    __hip_bfloat16* op = out + (size_t)t * 256 + h * 32 + d4;
    op[0] = __float2bfloat16(acc.x);
    op[1] = __float2bfloat16(acc.y);
    op[2] = __float2bfloat16(acc.z);
    op[3] = __float2bfloat16(acc.w);
}

// ---------------------------------------------------------------------------
// Residual + LayerNorm over D=256: one WAVE per row, shuffle reduce, no LDS.
// ---------------------------------------------------------------------------
__global__ __launch_bounds__(256)
void res_ln(const float* __restrict__ res, const float* __restrict__ proj,
            const float* __restrict__ g, const float* __restrict__ be,
            float* __restrict__ out, __hip_bfloat16* __restrict__ outb, int mode) {
    const int wave = threadIdx.x >> 6, lane = threadIdx.x & 63;
    const int r = blockIdx.x * 4 + wave;
    int t;
    if (mode == 0) t = r;
    else if (mode == 1) { int q = r / 136, m = r % 136; t = m * 100 + q; }
    else { int q = r / 136, rem = r % 136; int b = rem / 17, p = rem % 17; t = b * 1700 + q * 17 + p; }
    const int c4 = lane * 4;
    float4 a = *(const float4*)&res[(size_t)r * 256 + c4];
    float4 p = *(const float4*)&proj[(size_t)t * 256 + c4];
    float v[4] = {a.x + p.x, a.y + p.y, a.z + p.z, a.w + p.w};
    float s = v[0] + v[1] + v[2] + v[3];
#pragma unroll
    for (int off = 32; off > 0; off >>= 1) s += __shfl_xor(s, off);
    float mean = s * (1.f / 256.f);
    float d[4], ss = 0.f;
#pragma unroll
    for (int i = 0; i < 4; ++i) { d[i] = v[i] - mean; ss += d[i] * d[i]; }
#pragma unroll
    for (int off = 32; off > 0; off >>= 1) ss += __shfl_xor(ss, off);
    float rs = rsqrtf(ss * (1.f / 256.f) + 1e-5f);
    float4 gv = *(const float4*)&g[c4];
    float4 bv = *(const float4*)&be[c4];
    float o0 = d[0] * rs * gv.x + bv.x;
    float o1 = d[1] * rs * gv.y + bv.y;
    float o2 = d[2] * rs * gv.z + bv.z;
    float o3 = d[3] * rs * gv.w + bv.w;
    *(float4*)&out[(size_t)r * 256 + c4] = make_float4(o0, o1, o2, o3);
    if (outb) {
        bf16x4s ob = {f2bs(o0), f2bs(o1), f2bs(o2), f2bs(o3)};
        *(bf16x4s*)&outb[(size_t)r * 256 + c4] = ob;
    }
}

// ---------------------------------------------------------------------------
extern "C" void kernel_launch(void* const* d_in, const int* in_sizes, int n_in,
                              void* d_out, int out_size, void* d_ws, size_t ws_size,
                              hipStream_t stream) {
    const float* tgt    = (const float*)d_in[0];
    const float* qpos   = (const float*)d_in[1];
    const float* ref    = (const float*)d_in[2];
    const float* memory = (const float*)d_in[3];
    const float* w_in_w = (const float*)d_in[4];
    const float* b_in_w = (const float*)d_in[5];
    const float* w_out_w= (const float*)d_in[6];
    const float* b_out_w= (const float*)d_in[7];
    const float* w_in_a = (const float*)d_in[8];
    const float* b_in_a = (const float*)d_in[9];
    const float* w_out_a= (const float*)d_in[10];
    const float* b_out_a= (const float*)d_in[11];
    const float* w_off  = (const float*)d_in[12];
    const float* b_off  = (const float*)d_in[13];
    const float* w_aw   = (const float*)d_in[14];
    const float* b_aw   = (const float*)d_in[15];
    const float* w_val  = (const float*)d_in[16];
    const float* b_val  = (const float*)d_in[17];
    const float* w_oc   = (const float*)d_in[18];
    const float* b_oc   = (const float*)d_in[19];
    const float* g_w    = (const float*)d_in[20];
    const float* be_w   = (const float*)d_in[21];
    const float* g_a    = (const float*)d_in[22];
    const float* be_a   = (const float*)d_in[23];
    const float* g1     = (const float*)d_in[24];
    const float* be1    = (const float*)d_in[25];
    const float* g2     = (const float*)d_in[26];
    const float* be2    = (const float*)d_in[27];
    const float* w1     = (const float*)d_in[28];
    const float* b1     = (const float*)d_in[29];
    const float* w2     = (const float*)d_in[30];
    const float* b2     = (const float*)d_in[31];

    float* X  = (float*)d_out;
    float* ws = (float*)d_ws;
    float* R1 = ws;
    float* R2 = R1 + (size_t)MTOK * 256;
    float* R3 = R2 + (size_t)NTOK * 256;
    float* R6 = R3 + (size_t)NTOK * 128;
    float* QBF= R6 + (size_t)NTOK * 128;
    float* WBF= QBF+ (size_t)NTOK * 128;

    __hip_bfloat16* R1b = (__hip_bfloat16*)R1;
    __hip_bfloat16* R3b = (__hip_bfloat16*)R3;
    __hip_bfloat16* Qb  = (__hip_bfloat16*)QBF;
    __hip_bfloat16* Wb  = (__hip_bfloat16*)WBF;
    __hip_bfloat16* Hb  = (__hip_bfloat16*)R1;
    __hip_bfloat16* Vb  = (__hip_bfloat16*)R1;

    __hip_bfloat16* w_in_w_b  = Wb;
    __hip_bfloat16* w_out_w_b = Wb +  196608;
    __hip_bfloat16* w_in_a_b  = Wb +  262144;
    __hip_bfloat16* w_out_a_b = Wb +  458752;
    __hip_bfloat16* w_off_b   = Wb +  524288;
    __hip_bfloat16* w_aw_b    = Wb +  589824;
    __hip_bfloat16* w_val_b   = Wb +  622592;
    __hip_bfloat16* w_oc_b    = Wb +  688128;
    __hip_bfloat16* w1_b      = Wb +  753664;
    __hip_bfloat16* w2_b      = Wb + 1015808;

    cvt_weights<<<4992, 256, 0, stream>>>(w_in_w, w_out_w, w_in_a, w_out_a, w_off,
                                          w_aw, w_val, w_oc, w1, w2, Wb);

    const int MY64 = (NTOK + 63) / 64;   // 213

    // ---- Phase 1: group self-attention (S=17), gathers fused into A-path ----
    gemm64<2, true, false><<<dim3(8, MY64), 256, 0, stream>>>(
        tgt, qpos, w_in_w_b, b_in_w, R1b, NTOK, 256, 768, 0);              // QK = (tgt+qpos)W
    gemm64<1, true, false><<<dim3(4, MY64), 256, 0, stream>>>(
        tgt, nullptr, w_in_w_b + 512 * 256, b_in_w + 512, R1b, NTOK, 256, 768, 512);  // V
    attn17<<<dim3(800, 8), 256, 0, stream>>>(R1b, R3b);
    gemm64<0, false, false><<<dim3(4, MY64), 256, 0, stream>>>(
        R3b, nullptr, w_out_w_b, b_out_w, R2, NTOK, 256, 256, 0);
    res_ln<<<NTOK / 4, 256, 0, stream>>>(tgt, R2, g_w, be_w, X, nullptr, 0);

    // ---- Phase 2: query self-attention (S=100), y-order gather fused ----
    gemm64<3, true, false><<<dim3(12, MY64), 256, 0, stream>>>(
        X, nullptr, w_in_a_b, b_in_a, R1b, NTOK, 256, 768, 0);
    attn100<<<dim3(136, 8), 128, 0, stream>>>(R1b, R3b);
    gemm64<0, false, false><<<dim3(4, MY64), 256, 0, stream>>>(
        R3b, nullptr, w_out_a_b, b_out_a, R2, NTOK, 256, 256, 0);
    res_ln<<<NTOK / 4, 256, 0, stream>>>(X, R2, g_a, be_a, X, nullptr, 1);

    // ---- Phase 3: deformable attention (deform gather fused into qa) ----
    gemm64x<<<4 * ((MTOK + 63) / 64), 256, 0, stream>>>(
        memory, w_val_b, b_val, Vb, MTOK, 256, 256);
    gemm64qa<<<dim3(6, MY64), 256, 0, stream>>>(
        X, qpos, w_off_b, b_off, b_aw, R2, R6, NTOK, 256);
    deform_sample<<<NTOK / TPB, 256, 0, stream>>>(Vb, R2, R6, ref, R3b);
    gemm64<0, false, false><<<dim3(4, MY64), 256, 0, stream>>>(
        R3b, nullptr, w_oc_b, b_oc, R2, NTOK, 256, 256, 0);
    res_ln<<<NTOK / 4, 256, 0, stream>>>(X, R2, g1, be1, X, Qb, 2);

    // ---- Phase 4: FFN (64-tile machine fill) ----
    gemm64<0, true, true><<<dim3(16, MY64), 256, 0, stream>>>(
        Qb, nullptr, w1_b, b1, Hb, NTOK, 256, 1024, 0);                    // relu
    gemm64<0, false, false><<<dim3(4, MY64), 256, 0, stream>>>(
        Hb, nullptr, w2_b, b2, R2, NTOK, 1024, 256, 0);
    res_ln<<<NTOK / 4, 256, 0, stream>>>(X, R2, g2, be2, X, nullptr, 0);
}

// Round 25
// 323.318 us; speedup vs baseline: 1.0825x; 1.0825x over previous
//
#include <hip/hip_runtime.h>
#include <hip/hip_bf16.h>
#include <math.h>

#define NQd 100
#define BSd 8
#define NPTd 17
#define DIMd 256
#define NHd 8
#define DHd 32
#define DFFd 1024
#define NTOK (NQd*BSd*NPTd)        // 13600
#define LENIN 11253
#define MTOK (BSd*LENIN)           // 90024

typedef __attribute__((ext_vector_type(8))) short bf16x8;
typedef __attribute__((ext_vector_type(4))) short bf16x4s;
typedef __attribute__((ext_vector_type(4))) float f32x4;

__device__ inline short f2bs(float f) {
    __hip_bfloat16 h = __float2bfloat16(f);
    return *reinterpret_cast<short*>(&h);
}
__device__ inline float bs2f(short s) {
    return __uint_as_float(((unsigned)(unsigned short)s) << 16);
}

// ---------------------------------------------------------------------------
// 128x128 tile GEMM (FFN-up only, N=1024): 256 thr (4 waves 2x2), 4x4 frags,
// BK=32, LDS [buf][koct][129][8], dbuf, ONE barrier per K-tile.
// ---------------------------------------------------------------------------
template<bool RELU, bool OUT_BF16, bool A_FP32>
__global__ __launch_bounds__(256)
void gemm_mfma(const void* __restrict__ Av, const __hip_bfloat16* __restrict__ W,
               const float* __restrict__ bias, void* __restrict__ Cv,
               int M, int N, int K, int ldc, int col0) {
    __shared__ __hip_bfloat16 LA[2][4][129][8];
    __shared__ __hip_bfloat16 LW[2][4][129][8];
    const int tid = threadIdx.x;
    const int lane = tid & 63, wave = tid >> 6;
    const int wr = wave >> 1, wc = wave & 1;
    const int m0 = blockIdx.y * 128, n0 = blockIdx.x * 128;
    const int l15 = lane & 15, lg = lane >> 4;
    const int srow = tid >> 2, koct = tid & 3;
    bf16x8 aReg[2], wReg[2];

    auto load_tile = [&](int k0) {
#pragma unroll
        for (int it = 0; it < 2; ++it) {
            const int row = srow + it * 64;
            const int gm = m0 + row;
            bf16x8 av = {0, 0, 0, 0, 0, 0, 0, 0};
            if (A_FP32) {
                if (gm < M) {
                    const float* ap = (const float*)Av + (size_t)gm * K + k0 + koct * 8;
                    float4 f0 = *(const float4*)ap;
                    float4 f1 = *(const float4*)(ap + 4);
                    av = (bf16x8){f2bs(f0.x), f2bs(f0.y), f2bs(f0.z), f2bs(f0.w),
                                  f2bs(f1.x), f2bs(f1.y), f2bs(f1.z), f2bs(f1.w)};
                }
            } else {
                if (gm < M)
                    av = *(const bf16x8*)((const __hip_bfloat16*)Av + (size_t)gm * K + k0 + koct * 8);
            }
            aReg[it] = av;
            wReg[it] = *(const bf16x8*)(W + (size_t)(n0 + row) * K + k0 + koct * 8);
        }
    };
    auto write_tile = [&](int buf) {
#pragma unroll
        for (int it = 0; it < 2; ++it) {
            const int row = srow + it * 64;
            *(bf16x8*)&LA[buf][koct][row][0] = aReg[it];
            *(bf16x8*)&LW[buf][koct][row][0] = wReg[it];
        }
    };

    f32x4 acc[4][4];
#pragma unroll
    for (int i = 0; i < 4; ++i)
#pragma unroll
        for (int j = 0; j < 4; ++j) acc[i][j] = (f32x4){0.f, 0.f, 0.f, 0.f};

    const int NT = K >> 5;
    load_tile(0);
    write_tile(0);
    __syncthreads();
    for (int t = 0; t < NT; ++t) {
        const int cur = t & 1;
        if (t + 1 < NT) load_tile((t + 1) * 32);
        bf16x8 af[4], bfr[4];
#pragma unroll
        for (int f = 0; f < 4; ++f) {
            af[f]  = *(const bf16x8*)&LA[cur][lg][wr * 64 + f * 16 + l15][0];
            bfr[f] = *(const bf16x8*)&LW[cur][lg][wc * 64 + f * 16 + l15][0];
        }
#pragma unroll
        for (int fm = 0; fm < 4; ++fm)
#pragma unroll
            for (int fn = 0; fn < 4; ++fn)
                acc[fm][fn] = __builtin_amdgcn_mfma_f32_16x16x32_bf16(af[fm], bfr[fn], acc[fm][fn], 0, 0, 0);
        if (t + 1 < NT) write_tile(cur ^ 1);
        __syncthreads();
    }

#pragma unroll
    for (int fm = 0; fm < 4; ++fm) {
        const int row = m0 + wr * 64 + fm * 16 + lg * 4;
#pragma unroll
        for (int fn = 0; fn < 4; ++fn) {
            const int coln = n0 + wc * 64 + fn * 16 + l15;
            const float bsv = bias[coln];
#pragma unroll
            for (int r = 0; r < 4; ++r) {
                const int gr = row + r;
                if (gr >= M) continue;
                float v = acc[fm][fn][r] + bsv;
                if (RELU) v = fmaxf(v, 0.f);
                if (OUT_BF16)
                    ((__hip_bfloat16*)Cv)[(size_t)gr * ldc + col0 + coln] = __float2bfloat16(v);
                else
                    ((float*)Cv)[(size_t)gr * ldc + col0 + coln] = v;
            }
        }
    }
}

// ---------------------------------------------------------------------------
// 64x64-tile GEMM (machine fill): 256 thr, 4 waves 2x2, per-wave 32x32.
// Grid (N/64) x ceil(M/64).
// ---------------------------------------------------------------------------
template<bool A_FP32, bool OUT_BF16>
__global__ __launch_bounds__(256)
void gemm64(const void* __restrict__ Av, const __hip_bfloat16* __restrict__ W,
            const float* __restrict__ bias, void* __restrict__ Cv,
            int M, int K, int ldc, int col0) {
    __shared__ __hip_bfloat16 LA[2][4][65][8];
    __shared__ __hip_bfloat16 LW[2][4][65][8];
    const int tid = threadIdx.x;
    const int lane = tid & 63, wave = tid >> 6;
    const int wr = wave >> 1, wc = wave & 1;
    const int m0 = blockIdx.y * 64, n0 = blockIdx.x * 64;
    const int l15 = lane & 15, lg = lane >> 4;
    const int srow = tid >> 2, koct = tid & 3;
    const int gm = m0 + srow;
    const bool okA = gm < M;
    const __hip_bfloat16* pAb = (const __hip_bfloat16*)Av + (size_t)(okA ? gm : 0) * K + koct * 8;
    const float* pAf = (const float*)Av + (size_t)(okA ? gm : 0) * K + koct * 8;
    const __hip_bfloat16* pW = W + (size_t)(n0 + srow) * K + koct * 8;

    bf16x8 aR, wR;
    float4 f0R, f1R;
    auto load_tile = [&](int k0) {
        if (A_FP32) {
            f0R = okA ? *(const float4*)(pAf + k0)     : make_float4(0.f, 0.f, 0.f, 0.f);
            f1R = okA ? *(const float4*)(pAf + k0 + 4) : make_float4(0.f, 0.f, 0.f, 0.f);
        } else {
            aR = okA ? *(const bf16x8*)(pAb + k0) : (bf16x8){0, 0, 0, 0, 0, 0, 0, 0};
        }
        wR = *(const bf16x8*)(pW + k0);
    };
    auto write_tile = [&](int buf) {
        bf16x8 v;
        if (A_FP32)
            v = (bf16x8){f2bs(f0R.x), f2bs(f0R.y), f2bs(f0R.z), f2bs(f0R.w),
                         f2bs(f1R.x), f2bs(f1R.y), f2bs(f1R.z), f2bs(f1R.w)};
        else
            v = aR;
        *(bf16x8*)&LA[buf][koct][srow][0] = v;
        *(bf16x8*)&LW[buf][koct][srow][0] = wR;
    };

    f32x4 acc[2][2];
#pragma unroll
    for (int i = 0; i < 2; ++i)
#pragma unroll
        for (int j = 0; j < 2; ++j) acc[i][j] = (f32x4){0.f, 0.f, 0.f, 0.f};

    const int NT = K >> 5;
    load_tile(0);
    write_tile(0);
    __syncthreads();
    for (int t = 0; t < NT; ++t) {
        const int cur = t & 1;
        if (t + 1 < NT) load_tile((t + 1) * 32);
        bf16x8 af[2], bfr[2];
#pragma unroll
        for (int f = 0; f < 2; ++f) {
            af[f]  = *(const bf16x8*)&LA[cur][lg][wr * 32 + f * 16 + l15][0];
            bfr[f] = *(const bf16x8*)&LW[cur][lg][wc * 32 + f * 16 + l15][0];
        }
#pragma unroll
        for (int fm = 0; fm < 2; ++fm)
#pragma unroll
            for (int fn = 0; fn < 2; ++fn)
                acc[fm][fn] = __builtin_amdgcn_mfma_f32_16x16x32_bf16(af[fm], bfr[fn], acc[fm][fn], 0, 0, 0);
        if (t + 1 < NT) write_tile(cur ^ 1);
        __syncthreads();
    }

#pragma unroll
    for (int fm = 0; fm < 2; ++fm) {
        const int row = m0 + wr * 32 + fm * 16 + lg * 4;
#pragma unroll
        for (int fn = 0; fn < 2; ++fn) {
            const int coln = n0 + wc * 32 + fn * 16 + l15;
            const float bsv = bias[coln];
#pragma unroll
            for (int r = 0; r < 4; ++r) {
                const int gr = row + r;
                if (gr >= M) continue;
                float v = acc[fm][fn][r] + bsv;
                if (OUT_BF16)
                    ((__hip_bfloat16*)Cv)[(size_t)gr * ldc + col0 + coln] = __float2bfloat16(v);
                else
                    ((float*)Cv)[(size_t)gr * ldc + col0 + coln] = v;
            }
        }
    }
}

// ---------------------------------------------------------------------------
// gemm64qa: fused offsets+attn-weights projection. A = Qb (bf16), W = packed
// [w_off (256 rows) | w_aw (128 rows)] contiguous, N = 384. Split epilogue:
// cols <256 -> Coff (fp32, ld 256); cols >=256 -> Caw (fp32, ld 128).
// ---------------------------------------------------------------------------
__global__ __launch_bounds__(256)
void gemm64qa(const __hip_bfloat16* __restrict__ Ab, const __hip_bfloat16* __restrict__ W,
              const float* __restrict__ boff, const float* __restrict__ baw,
              float* __restrict__ Coff, float* __restrict__ Caw, int M, int K) {
    __shared__ __hip_bfloat16 LA[2][4][65][8];
    __shared__ __hip_bfloat16 LW[2][4][65][8];
    const int tid = threadIdx.x;
    const int lane = tid & 63, wave = tid >> 6;
    const int wr = wave >> 1, wc = wave & 1;
    const int m0 = blockIdx.y * 64, n0 = blockIdx.x * 64;
    const int l15 = lane & 15, lg = lane >> 4;
    const int srow = tid >> 2, koct = tid & 3;
    const int gm = m0 + srow;
    const bool okA = gm < M;
    const __hip_bfloat16* pAb = Ab + (size_t)(okA ? gm : 0) * K + koct * 8;
    const __hip_bfloat16* pW = W + (size_t)(n0 + srow) * K + koct * 8;

    bf16x8 aR, wR;
    auto load_tile = [&](int k0) {
        aR = okA ? *(const bf16x8*)(pAb + k0) : (bf16x8){0, 0, 0, 0, 0, 0, 0, 0};
        wR = *(const bf16x8*)(pW + k0);
    };
    auto write_tile = [&](int buf) {
        *(bf16x8*)&LA[buf][koct][srow][0] = aR;
        *(bf16x8*)&LW[buf][koct][srow][0] = wR;
    };

    f32x4 acc[2][2];
#pragma unroll
    for (int i = 0; i < 2; ++i)
#pragma unroll
        for (int j = 0; j < 2; ++j) acc[i][j] = (f32x4){0.f, 0.f, 0.f, 0.f};

    const int NT = K >> 5;
    load_tile(0);
    write_tile(0);
    __syncthreads();
    for (int t = 0; t < NT; ++t) {
        const int cur = t & 1;
        if (t + 1 < NT) load_tile((t + 1) * 32);
        bf16x8 af[2], bfr[2];
#pragma unroll
        for (int f = 0; f < 2; ++f) {
            af[f]  = *(const bf16x8*)&LA[cur][lg][wr * 32 + f * 16 + l15][0];
            bfr[f] = *(const bf16x8*)&LW[cur][lg][wc * 32 + f * 16 + l15][0];
        }
#pragma unroll
        for (int fm = 0; fm < 2; ++fm)
#pragma unroll
            for (int fn = 0; fn < 2; ++fn)
                acc[fm][fn] = __builtin_amdgcn_mfma_f32_16x16x32_bf16(af[fm], bfr[fn], acc[fm][fn], 0, 0, 0);
        if (t + 1 < NT) write_tile(cur ^ 1);
        __syncthreads();
    }

#pragma unroll
    for (int fm = 0; fm < 2; ++fm) {
        const int row = m0 + wr * 32 + fm * 16 + lg * 4;
#pragma unroll
        for (int fn = 0; fn < 2; ++fn) {
            const int coln = n0 + wc * 32 + fn * 16 + l15;
#pragma unroll
            for (int r = 0; r < 4; ++r) {
                const int gr = row + r;
                if (gr >= M) continue;
                if (coln < 256) {
                    Coff[(size_t)gr * 256 + coln] = acc[fm][fn][r] + boff[coln];
                } else {
                    Caw[(size_t)gr * 128 + (coln - 256)] = acc[fm][fn][r] + baw[coln - 256];
                }
            }
        }
    }
}

// ---------------------------------------------------------------------------
// gemm64x: value projection (M=90024, N=256, fp32 A -> bf16 C).
// 5628 blocks + m204 bijective XCD-chunked swizzle (FETCH 45.6 MB measured).
// ---------------------------------------------------------------------------
__global__ __launch_bounds__(256)
void gemm64x(const float* __restrict__ Av, const __hip_bfloat16* __restrict__ W,
             const float* __restrict__ bias, __hip_bfloat16* __restrict__ Cv,
             int M, int K, int ldc) {
    const int nwg = gridDim.x;
    const int orig = blockIdx.x;
    const int xcd = orig & 7, loc = orig >> 3;
    const int q = nwg >> 3, r = nwg & 7;
    const int swz = (xcd < r ? xcd * (q + 1) : r * (q + 1) + (xcd - r) * q) + loc;
    const int m0 = (swz >> 2) * 64, n0 = (swz & 3) * 64;

    __shared__ __hip_bfloat16 LA[2][4][65][8];
    __shared__ __hip_bfloat16 LW[2][4][65][8];
    const int tid = threadIdx.x;
    const int lane = tid & 63, wave = tid >> 6;
    const int wr = wave >> 1, wc = wave & 1;
    const int l15 = lane & 15, lg = lane >> 4;
    const int srow = tid >> 2, koct = tid & 3;
    const int gm = m0 + srow;
    const bool okA = gm < M;
    const float* pAf = Av + (size_t)(okA ? gm : 0) * K + koct * 8;
    const __hip_bfloat16* pW = W + (size_t)(n0 + srow) * K + koct * 8;

    bf16x8 wR;
    float4 f0R, f1R;
    auto load_tile = [&](int k0) {
        f0R = okA ? *(const float4*)(pAf + k0)     : make_float4(0.f, 0.f, 0.f, 0.f);
        f1R = okA ? *(const float4*)(pAf + k0 + 4) : make_float4(0.f, 0.f, 0.f, 0.f);
        wR = *(const bf16x8*)(pW + k0);
    };
    auto write_tile = [&](int buf) {
        *(bf16x8*)&LA[buf][koct][srow][0] =
            (bf16x8){f2bs(f0R.x), f2bs(f0R.y), f2bs(f0R.z), f2bs(f0R.w),
                     f2bs(f1R.x), f2bs(f1R.y), f2bs(f1R.z), f2bs(f1R.w)};
        *(bf16x8*)&LW[buf][koct][srow][0] = wR;
    };

    f32x4 acc[2][2];
#pragma unroll
    for (int i = 0; i < 2; ++i)
#pragma unroll
        for (int j = 0; j < 2; ++j) acc[i][j] = (f32x4){0.f, 0.f, 0.f, 0.f};

    const int NT = K >> 5;
    load_tile(0);
    write_tile(0);
    __syncthreads();
    for (int t = 0; t < NT; ++t) {
        const int cur = t & 1;
        if (t + 1 < NT) load_tile((t + 1) * 32);
        bf16x8 af[2], bfr[2];
#pragma unroll
        for (int f = 0; f < 2; ++f) {
            af[f]  = *(const bf16x8*)&LA[cur][lg][wr * 32 + f * 16 + l15][0];
            bfr[f] = *(const bf16x8*)&LW[cur][lg][wc * 32 + f * 16 + l15][0];
        }
#pragma unroll
        for (int fm = 0; fm < 2; ++fm)
#pragma unroll
            for (int fn = 0; fn < 2; ++fn)
                acc[fm][fn] = __builtin_amdgcn_mfma_f32_16x16x32_bf16(af[fm], bfr[fn], acc[fm][fn], 0, 0, 0);
        if (t + 1 < NT) write_tile(cur ^ 1);
        __syncthreads();
    }

#pragma unroll
    for (int fm = 0; fm < 2; ++fm) {
        const int row = m0 + wr * 32 + fm * 16 + lg * 4;
#pragma unroll
        for (int fn = 0; fn < 2; ++fn) {
            const int coln = n0 + wc * 32 + fn * 16 + l15;
            const float bsv = bias[coln];
#pragma unroll
            for (int r = 0; r < 4; ++r) {
                const int gr = row + r;
                if (gr >= M) continue;
                Cv[(size_t)gr * ldc + coln] = __float2bfloat16(acc[fm][fn][r] + bsv);
            }
        }
    }
}

// ---------------------------------------------------------------------------
// Fused weight conversion fp32 -> bf16 into one packed buffer.
// ---------------------------------------------------------------------------
__global__ void cvt_weights(const float* w0, const float* w1, const float* w2,
                            const float* w3, const float* w4, const float* w5,
                            const float* w6, const float* w7, const float* w8,
                            const float* w9, __hip_bfloat16* dst) {
    int idx = blockIdx.x * 256 + threadIdx.x;
    float v;
    if      (idx <  196608) v = w0[idx];
    else if (idx <  262144) v = w1[idx -  196608];
    else if (idx <  458752) v = w2[idx -  262144];
    else if (idx <  524288) v = w3[idx -  458752];
    else if (idx <  589824) v = w4[idx -  524288];
    else if (idx <  622592) v = w5[idx -  589824];
    else if (idx <  688128) v = w6[idx -  622592];
    else if (idx <  753664) v = w7[idx -  688128];
    else if (idx < 1015808) v = w8[idx -  753664];
    else                    v = w9[idx - 1015808];
    dst[idx] = __float2bfloat16(v);
}

// ---------------------------------------------------------------------------
// Row gather (+optional add) -> contiguous bf16 (t, 256) buffer.
// ---------------------------------------------------------------------------
__global__ void gather_rows_b(const float* __restrict__ src, const float* __restrict__ add,
                              __hip_bfloat16* __restrict__ dst, int mode) {
    int t = blockIdx.x, c = threadIdx.x;
    int r;
    if (mode == 0) r = t;
    else if (mode == 1) { int m = t / 100, q = t % 100; r = q * 136 + m; }
    else { int b = t / 1700, jj = t % 1700; int q = jj / 17, p = jj % 17; r = q * 136 + b * 17 + p; }
    float v = src[(size_t)r * 256 + c];
    if (add) v += add[(size_t)r * 256 + c];
    dst[(size_t)t * 256 + c] = __float2bfloat16(v);
}

// ---------------------------------------------------------------------------
// MHA S=17 (group attention). qkv BF16 rows t*768 (Q|K|V). block=(group, head)
// ---------------------------------------------------------------------------
__global__ void attn17(const __hip_bfloat16* __restrict__ qkv, __hip_bfloat16* __restrict__ out) {
    const int g = blockIdx.x, h = blockIdx.y;
    __shared__ float q[17][32], k[17][32], v[17][32], s[17][18];
    const int tid = threadIdx.x;  // 256
    for (int idx = tid; idx < 17 * 32; idx += 256) {
        int i = idx >> 5, d = idx & 31;
        size_t row = (size_t)(g * 17 + i) * 768 + h * 32 + d;
        q[i][d] = bs2f(*(const short*)&qkv[row]);
        k[i][d] = bs2f(*(const short*)&qkv[row + 256]);
        v[i][d] = bs2f(*(const short*)&qkv[row + 512]);
    }
    __syncthreads();
    for (int idx = tid; idx < 17 * 17; idx += 256) {
        int i = idx / 17, j = idx % 17;
        float acc = 0.f;
#pragma unroll
        for (int d = 0; d < 32; ++d) acc += q[i][d] * k[j][d];
        s[i][j] = acc * 0.17677669529663688f;
    }
    __syncthreads();
    if (tid < 17) {
        float m = -1e30f;
        for (int j = 0; j < 17; ++j) m = fmaxf(m, s[tid][j]);
        float sum = 0.f;
        for (int j = 0; j < 17; ++j) { float e = __expf(s[tid][j] - m); s[tid][j] = e; sum += e; }
        float inv = 1.f / sum;
        for (int j = 0; j < 17; ++j) s[tid][j] *= inv;
    }
    __syncthreads();
    for (int idx = tid; idx < 17 * 32; idx += 256) {
        int i = idx >> 5, d = idx & 31;
        float acc = 0.f;
        for (int j = 0; j < 17; ++j) acc += s[i][j] * v[j][d];
        out[(size_t)(g * 17 + i) * 256 + h * 32 + d] = __float2bfloat16(acc);
    }
}

// ---------------------------------------------------------------------------
// MHA S=100 v2: MFMA flash per (group, head). 128 thr = 2 waves. qkv BF16.
// ---------------------------------------------------------------------------
__global__ __launch_bounds__(128)
void attn100(const __hip_bfloat16* __restrict__ qkv, __hip_bfloat16* __restrict__ out) {
    const int g = blockIdx.x, h = blockIdx.y;
    __shared__ __hip_bfloat16 Vt[32][136];
    __shared__ __hip_bfloat16 Pl[2][16][136];
    const int tid = threadIdx.x;
    const int wave = tid >> 6, lane = tid & 63;
    const int l15 = lane & 15, lg = lane >> 4;

    for (int idx = tid; idx < 3200; idx += 128) {
        int j = idx >> 5, d = idx & 31;
        Vt[d][j] = qkv[(size_t)(g * 100 + j) * 768 + 512 + h * 32 + d];
    }
    for (int idx = tid; idx < 32 * 28; idx += 128) {
        int d = idx & 31, jz = 100 + (idx >> 5);
        Vt[d][jz] = __float2bfloat16(0.f);
    }
    __syncthreads();

    const int rt0 = wave ? 4 : 0, rt1 = wave ? 7 : 4;
    for (int rt = rt0; rt < rt1; ++rt) {
        const int rowbase = rt * 16;
        int qr = rowbase + l15; if (qr > 99) qr = 99;
        bf16x8 aq = *(const bf16x8*)(qkv + (size_t)(g * 100 + qr) * 768 + h * 32 + lg * 8);
        f32x4 s[7];
#pragma unroll
        for (int jt = 0; jt < 7; ++jt) {
            int jr = jt * 16 + l15; if (jr > 99) jr = 99;
            bf16x8 bk = *(const bf16x8*)(qkv + (size_t)(g * 100 + jr) * 768 + 256 + h * 32 + lg * 8);
            s[jt] = __builtin_amdgcn_mfma_f32_16x16x32_bf16(aq, bk, (f32x4){0.f, 0.f, 0.f, 0.f}, 0, 0, 0);
        }
        float mr[4] = {-1e30f, -1e30f, -1e30f, -1e30f};
#pragma unroll
        for (int jt = 0; jt < 7; ++jt) {
            const bool valid = (jt * 16 + l15) < 100;
#pragma unroll
            for (int r = 0; r < 4; ++r) {
                float v = valid ? s[jt][r] * 0.17677669529663688f : -1e30f;
                s[jt][r] = v;
                mr[r] = fmaxf(mr[r], v);
            }
        }
#pragma unroll
        for (int r = 0; r < 4; ++r) {
            mr[r] = fmaxf(mr[r], __shfl_xor(mr[r], 1));
            mr[r] = fmaxf(mr[r], __shfl_xor(mr[r], 2));
            mr[r] = fmaxf(mr[r], __shfl_xor(mr[r], 4));
            mr[r] = fmaxf(mr[r], __shfl_xor(mr[r], 8));
        }
        float lr[4] = {0.f, 0.f, 0.f, 0.f};
#pragma unroll
        for (int jt = 0; jt < 7; ++jt)
#pragma unroll
            for (int r = 0; r < 4; ++r) {
                float e = __expf(s[jt][r] - mr[r]);
                s[jt][r] = e;
                lr[r] += e;
            }
#pragma unroll
        for (int r = 0; r < 4; ++r) {
            lr[r] += __shfl_xor(lr[r], 1);
            lr[r] += __shfl_xor(lr[r], 2);
            lr[r] += __shfl_xor(lr[r], 4);
            lr[r] += __shfl_xor(lr[r], 8);
        }
#pragma unroll
        for (int jt = 0; jt < 7; ++jt)
#pragma unroll
            for (int r = 0; r < 4; ++r)
                Pl[wave][lg * 4 + r][jt * 16 + l15] = __float2bfloat16(s[jt][r]);
#pragma unroll
        for (int r = 0; r < 4; ++r)
            Pl[wave][lg * 4 + r][112 + l15] = __float2bfloat16(0.f);

        f32x4 o0 = (f32x4){0.f, 0.f, 0.f, 0.f};
        f32x4 o1 = (f32x4){0.f, 0.f, 0.f, 0.f};
#pragma unroll
        for (int c = 0; c < 4; ++c) {
            bf16x8 pa = *(const bf16x8*)&Pl[wave][l15][c * 32 + lg * 8];
            bf16x8 v0 = *(const bf16x8*)&Vt[l15][c * 32 + lg * 8];
            bf16x8 v1 = *(const bf16x8*)&Vt[16 + l15][c * 32 + lg * 8];
            o0 = __builtin_amdgcn_mfma_f32_16x16x32_bf16(pa, v0, o0, 0, 0, 0);
            o1 = __builtin_amdgcn_mfma_f32_16x16x32_bf16(pa, v1, o1, 0, 0, 0);
        }
#pragma unroll
        for (int r = 0; r < 4; ++r) {
            int row = rowbase + lg * 4 + r;
            if (row < 100) {
                float inv = 1.f / lr[r];
                __hip_bfloat16* op = out + (size_t)(g * 100 + row) * 256 + h * 32;
                op[l15]      = __float2bfloat16(o0[r] * inv);
                op[16 + l15] = __float2bfloat16(o1[r] * inv);
            }
        }
    }
}

// ---------------------------------------------------------------------------
// Deformable sampling: bf16 value input. block = 4 tokens, 256 threads.
// ---------------------------------------------------------------------------
#define TPB 4
__global__ __launch_bounds__(256)
void deform_sample(const __hip_bfloat16* __restrict__ value, const float* __restrict__ off,
                   const float* __restrict__ aw, const float* __restrict__ ref,
                   __hip_bfloat16* __restrict__ out) {
    const int t0 = blockIdx.x * TPB;
    const int tid = threadIdx.x;
    __shared__ float raw[TPB][128];
    __shared__ float wgt[TPB][128];
    __shared__ int   cidx[TPB][128][4];
    __shared__ float cw[TPB][128][4];

    for (int idx = tid; idx < TPB * 128; idx += 256) {
        int tk = idx >> 7, i = idx & 127;
        raw[tk][i] = aw[(size_t)(t0 + tk) * 128 + i];
    }
    __syncthreads();
    if (tid < TPB * 8) {
        int tk = tid >> 3, h = tid & 7;
        float m = -1e30f;
        for (int i = 0; i < 16; ++i) m = fmaxf(m, raw[tk][h * 16 + i]);
        float sum = 0.f;
        float e[16];
        for (int i = 0; i < 16; ++i) { e[i] = __expf(raw[tk][h * 16 + i] - m); sum += e[i]; }
        float inv = 1.f / sum;
        for (int i = 0; i < 16; ++i) wgt[tk][h * 16 + i] = e[i] * inv;
    }
    __syncthreads();

    const int Hs[4] = {92, 46, 23, 12};
    const int Sts[4] = {0, 8464, 10580, 11109};
    for (int s = tid; s < TPB * 128; s += 256) {
        int tk = s >> 7, sid = s & 127;
        int t = t0 + tk;
        int b = t / 1700, jj = t % 1700;
        int q = jj / 17, p = jj % 17;
        int l = (sid >> 2) & 3;
        int HW = Hs[l];
        float HWf = (float)HW;
        const float* refp = ref + (size_t)((q * 8 + b) * 17 + p) * 8;
        float rx = refp[l * 2], ry = refp[l * 2 + 1];
        float ox = off[(size_t)t * 256 + sid * 2];
        float oy = off[(size_t)t * 256 + sid * 2 + 1];
        float x = (rx + ox / HWf) * HWf - 0.5f;
        float y = (ry + oy / HWf) * HWf - 0.5f;
        float x0f = floorf(x), y0f = floorf(y);
        float wx = x - x0f, wy = y - y0f;
        int xi = (int)x0f, yi = (int)y0f;
        float wg = wgt[tk][sid];
#pragma unroll
        for (int c = 0; c < 4; ++c) {
            int cy = c >> 1, cx = c & 1;
            int yy = yi + cy, xx = xi + cx;
            bool ok = (xx >= 0) && (xx < HW) && (yy >= 0) && (yy < HW);
            int yc = min(max(yy, 0), HW - 1);
            int xc = min(max(xx, 0), HW - 1);
            cidx[tk][sid][c] = Sts[l] + yc * HW + xc;
            float w = (cy ? wy : 1.f - wy) * (cx ? wx : 1.f - wx);
            cw[tk][sid][c] = ok ? wg * w : 0.f;
        }
    }
    __syncthreads();

    const int tk = tid >> 6, lane = tid & 63;
    const int h = lane >> 3, d4 = (lane & 7) * 4;
    const int t = t0 + tk;
    const int b = t / 1700;
    const __hip_bfloat16* vb = value + (size_t)b * LENIN * 256 + h * 32 + d4;
    float4 acc = make_float4(0.f, 0.f, 0.f, 0.f);
    for (int s16 = 0; s16 < 16; ++s16) {
        int sid = h * 16 + s16;
#pragma unroll
        for (int c = 0; c < 4; ++c) {
            int idx = cidx[tk][sid][c];
            float w = cw[tk][sid][c];
            bf16x4s v = *(const bf16x4s*)(vb + (size_t)idx * 256);
            acc.x += w * bs2f(v.x); acc.y += w * bs2f(v.y);
            acc.z += w * bs2f(v.z); acc.w += w * bs2f(v.w);
        }
    }
    __hip_bfloat16* op = out + (size_t)t * 256 + h * 32 + d4;
    op[0] = __float2bfloat16(acc.x);
    op[1] = __float2bfloat16(acc.y);
    op[2] = __float2bfloat16(acc.z);
    op[3] = __float2bfloat16(acc.w);
}

// ---------------------------------------------------------------------------
// Residual + LayerNorm over D=256: one WAVE per row, shuffle reduce, no LDS.
// ---------------------------------------------------------------------------
__global__ __launch_bounds__(256)
void res_ln(const float* __restrict__ res, const float* __restrict__ proj,
            const float* __restrict__ g, const float* __restrict__ be,
            float* __restrict__ out, __hip_bfloat16* __restrict__ outb, int mode) {
    const int wave = threadIdx.x >> 6, lane = threadIdx.x & 63;
    const int r = blockIdx.x * 4 + wave;
    int t;
    if (mode == 0) t = r;
    else if (mode == 1) { int q = r / 136, m = r % 136; t = m * 100 + q; }
    else { int q = r / 136, rem = r % 136; int b = rem / 17, p = rem % 17; t = b * 1700 + q * 17 + p; }
    const int c4 = lane * 4;
    float4 a = *(const float4*)&res[(size_t)r * 256 + c4];
    float4 p = *(const float4*)&proj[(size_t)t * 256 + c4];
    float v[4] = {a.x + p.x, a.y + p.y, a.z + p.z, a.w + p.w};
    float s = v[0] + v[1] + v[2] + v[3];
#pragma unroll
    for (int off = 32; off > 0; off >>= 1) s += __shfl_xor(s, off);
    float mean = s * (1.f / 256.f);
    float d[4], ss = 0.f;
#pragma unroll
    for (int i = 0; i < 4; ++i) { d[i] = v[i] - mean; ss += d[i] * d[i]; }
#pragma unroll
    for (int off = 32; off > 0; off >>= 1) ss += __shfl_xor(ss, off);
    float rs = rsqrtf(ss * (1.f / 256.f) + 1e-5f);
    float4 gv = *(const float4*)&g[c4];
    float4 bv = *(const float4*)&be[c4];
    float o0 = d[0] * rs * gv.x + bv.x;
    float o1 = d[1] * rs * gv.y + bv.y;
    float o2 = d[2] * rs * gv.z + bv.z;
    float o3 = d[3] * rs * gv.w + bv.w;
    *(float4*)&out[(size_t)r * 256 + c4] = make_float4(o0, o1, o2, o3);
    if (outb) {
        bf16x4s ob = {f2bs(o0), f2bs(o1), f2bs(o2), f2bs(o3)};
        *(bf16x4s*)&outb[(size_t)r * 256 + c4] = ob;
    }
}

// ---------------------------------------------------------------------------
extern "C" void kernel_launch(void* const* d_in, const int* in_sizes, int n_in,
                              void* d_out, int out_size, void* d_ws, size_t ws_size,
                              hipStream_t stream) {
    const float* tgt    = (const float*)d_in[0];
    const float* qpos   = (const float*)d_in[1];
    const float* ref    = (const float*)d_in[2];
    const float* memory = (const float*)d_in[3];
    const float* w_in_w = (const float*)d_in[4];
    const float* b_in_w = (const float*)d_in[5];
    const float* w_out_w= (const float*)d_in[6];
    const float* b_out_w= (const float*)d_in[7];
    const float* w_in_a = (const float*)d_in[8];
    const float* b_in_a = (const float*)d_in[9];
    const float* w_out_a= (const float*)d_in[10];
    const float* b_out_a= (const float*)d_in[11];
    const float* w_off  = (const float*)d_in[12];
    const float* b_off  = (const float*)d_in[13];
    const float* w_aw   = (const float*)d_in[14];
    const float* b_aw   = (const float*)d_in[15];
    const float* w_val  = (const float*)d_in[16];
    const float* b_val  = (const float*)d_in[17];
    const float* w_oc   = (const float*)d_in[18];
    const float* b_oc   = (const float*)d_in[19];
    const float* g_w    = (const float*)d_in[20];
    const float* be_w   = (const float*)d_in[21];
    const float* g_a    = (const float*)d_in[22];
    const float* be_a   = (const float*)d_in[23];
    const float* g1     = (const float*)d_in[24];
    const float* be1    = (const float*)d_in[25];
    const float* g2     = (const float*)d_in[26];
    const float* be2    = (const float*)d_in[27];
    const float* w1     = (const float*)d_in[28];
    const float* b1     = (const float*)d_in[29];
    const float* w2     = (const float*)d_in[30];
    const float* b2     = (const float*)d_in[31];

    float* X  = (float*)d_out;
    float* ws = (float*)d_ws;
    float* R1 = ws;
    float* R2 = R1 + (size_t)MTOK * 256;
    float* R3 = R2 + (size_t)NTOK * 256;
    float* R6 = R3 + (size_t)NTOK * 128;
    float* QBF= R6 + (size_t)NTOK * 128;
    float* WBF= QBF+ (size_t)NTOK * 128;

    __hip_bfloat16* R1b = (__hip_bfloat16*)R1;
    __hip_bfloat16* R3b = (__hip_bfloat16*)R3;
    __hip_bfloat16* Qb  = (__hip_bfloat16*)QBF;
    __hip_bfloat16* Wb  = (__hip_bfloat16*)WBF;
    __hip_bfloat16* Hb  = (__hip_bfloat16*)R1;
    __hip_bfloat16* Vb  = (__hip_bfloat16*)R1;

    __hip_bfloat16* w_in_w_b  = Wb;
    __hip_bfloat16* w_out_w_b = Wb +  196608;
    __hip_bfloat16* w_in_a_b  = Wb +  262144;
    __hip_bfloat16* w_out_a_b = Wb +  458752;
    __hip_bfloat16* w_off_b   = Wb +  524288;
    __hip_bfloat16* w_aw_b    = Wb +  589824;
    __hip_bfloat16* w_val_b   = Wb +  622592;
    __hip_bfloat16* w_oc_b    = Wb +  688128;
    __hip_bfloat16* w1_b      = Wb +  753664;
    __hip_bfloat16* w2_b      = Wb + 1015808;

    cvt_weights<<<4992, 256, 0, stream>>>(w_in_w, w_out_w, w_in_a, w_out_a, w_off,
                                          w_aw, w_val, w_oc, w1, w2, Wb);

    const int MY64 = (NTOK + 63) / 64;   // 213

    // ---- Phase 1: group self-attention (S=17), qkv bf16, all-64-tile ----
    gather_rows_b<<<NTOK, 256, 0, stream>>>(tgt, qpos, Qb, 0);
    gemm64<false, true><<<dim3(8, MY64), 256, 0, stream>>>(
        Qb, w_in_w_b, b_in_w, R1b, NTOK, 256, 768, 0);
    gemm64<true, true><<<dim3(4, MY64), 256, 0, stream>>>(
        tgt, w_in_w_b + 512 * 256, b_in_w + 512, R1b, NTOK, 256, 768, 512);
    attn17<<<dim3(800, 8), 256, 0, stream>>>(R1b, R3b);
    gemm64<false, false><<<dim3(4, MY64), 256, 0, stream>>>(
        R3b, w_out_w_b, b_out_w, R2, NTOK, 256, 256, 0);
    res_ln<<<NTOK / 4, 256, 0, stream>>>(tgt, R2, g_w, be_w, X, nullptr, 0);

    // ---- Phase 2: query self-attention (S=100), qkv bf16, all-64-tile ----
    gather_rows_b<<<NTOK, 256, 0, stream>>>(X, nullptr, Qb, 1);
    gemm64<false, true><<<dim3(12, MY64), 256, 0, stream>>>(
        Qb, w_in_a_b, b_in_a, R1b, NTOK, 256, 768, 0);
    attn100<<<dim3(136, 8), 128, 0, stream>>>(R1b, R3b);
    gemm64<false, false><<<dim3(4, MY64), 256, 0, stream>>>(
        R3b, w_out_a_b, b_out_a, R2, NTOK, 256, 256, 0);
    res_ln<<<NTOK / 4, 256, 0, stream>>>(X, R2, g_a, be_a, X, nullptr, 1);

    // ---- Phase 3: deformable attention ----
    gemm64x<<<4 * ((MTOK + 63) / 64), 256, 0, stream>>>(
        memory, w_val_b, b_val, Vb, MTOK, 256, 256);
    gather_rows_b<<<NTOK, 256, 0, stream>>>(X, qpos, Qb, 2);
    gemm64qa<<<dim3(6, MY64), 256, 0, stream>>>(
        Qb, w_off_b, b_off, b_aw, R2, R6, NTOK, 256);   // off+aw fused (W rows contiguous)
    deform_sample<<<NTOK / TPB, 256, 0, stream>>>(Vb, R2, R6, ref, R3b);
    gemm64<false, false><<<dim3(4, MY64), 256, 0, stream>>>(
        R3b, w_oc_b, b_oc, R2, NTOK, 256, 256, 0);
    res_ln<<<NTOK / 4, 256, 0, stream>>>(X, R2, g1, be1, X, Qb, 2);

    // ---- Phase 4: FFN ----
    gemm_mfma<true, true, false><<<dim3(8, (NTOK + 127) / 128), 256, 0, stream>>>(
        Qb, w1_b, b1, Hb, NTOK, 1024, 256, 1024, 0);
    gemm64<false, false><<<dim3(4, MY64), 256, 0, stream>>>(
        (const __hip_bfloat16*)Hb, w2_b, b2, R2, NTOK, 1024, 256, 0);
    res_ln<<<NTOK / 4, 256, 0, stream>>>(X, R2, g2, be2, X, nullptr, 0);
}

// Round 26
// 322.548 us; speedup vs baseline: 1.0851x; 1.0024x over previous
//
#include <hip/hip_runtime.h>
#include <hip/hip_bf16.h>
#include <math.h>

#define NQd 100
#define BSd 8
#define NPTd 17
#define DIMd 256
#define NHd 8
#define DHd 32
#define DFFd 1024
#define NTOK (NQd*BSd*NPTd)        // 13600
#define LENIN 11253
#define MTOK (BSd*LENIN)           // 90024

typedef __attribute__((ext_vector_type(8))) short bf16x8;
typedef __attribute__((ext_vector_type(4))) short bf16x4s;
typedef __attribute__((ext_vector_type(4))) float f32x4;

__device__ inline short f2bs(float f) {
    __hip_bfloat16 h = __float2bfloat16(f);
    return *reinterpret_cast<short*>(&h);
}
__device__ inline float bs2f(short s) {
    return __uint_as_float(((unsigned)(unsigned short)s) << 16);
}

// ---------------------------------------------------------------------------
// 128x128 tile GEMM (FFN-up only, N=1024): 256 thr (4 waves 2x2), 4x4 frags,
// BK=32, LDS [buf][koct][129][8], dbuf, ONE barrier per K-tile.
// ---------------------------------------------------------------------------
template<bool RELU, bool OUT_BF16, bool A_FP32>
__global__ __launch_bounds__(256)
void gemm_mfma(const void* __restrict__ Av, const __hip_bfloat16* __restrict__ W,
               const float* __restrict__ bias, void* __restrict__ Cv,
               int M, int N, int K, int ldc, int col0) {
    __shared__ __hip_bfloat16 LA[2][4][129][8];
    __shared__ __hip_bfloat16 LW[2][4][129][8];
    const int tid = threadIdx.x;
    const int lane = tid & 63, wave = tid >> 6;
    const int wr = wave >> 1, wc = wave & 1;
    const int m0 = blockIdx.y * 128, n0 = blockIdx.x * 128;
    const int l15 = lane & 15, lg = lane >> 4;
    const int srow = tid >> 2, koct = tid & 3;
    bf16x8 aReg[2], wReg[2];

    auto load_tile = [&](int k0) {
#pragma unroll
        for (int it = 0; it < 2; ++it) {
            const int row = srow + it * 64;
            const int gm = m0 + row;
            bf16x8 av = {0, 0, 0, 0, 0, 0, 0, 0};
            if (A_FP32) {
                if (gm < M) {
                    const float* ap = (const float*)Av + (size_t)gm * K + k0 + koct * 8;
                    float4 f0 = *(const float4*)ap;
                    float4 f1 = *(const float4*)(ap + 4);
                    av = (bf16x8){f2bs(f0.x), f2bs(f0.y), f2bs(f0.z), f2bs(f0.w),
                                  f2bs(f1.x), f2bs(f1.y), f2bs(f1.z), f2bs(f1.w)};
                }
            } else {
                if (gm < M)
                    av = *(const bf16x8*)((const __hip_bfloat16*)Av + (size_t)gm * K + k0 + koct * 8);
            }
            aReg[it] = av;
            wReg[it] = *(const bf16x8*)(W + (size_t)(n0 + row) * K + k0 + koct * 8);
        }
    };
    auto write_tile = [&](int buf) {
#pragma unroll
        for (int it = 0; it < 2; ++it) {
            const int row = srow + it * 64;
            *(bf16x8*)&LA[buf][koct][row][0] = aReg[it];
            *(bf16x8*)&LW[buf][koct][row][0] = wReg[it];
        }
    };

    f32x4 acc[4][4];
#pragma unroll
    for (int i = 0; i < 4; ++i)
#pragma unroll
        for (int j = 0; j < 4; ++j) acc[i][j] = (f32x4){0.f, 0.f, 0.f, 0.f};

    const int NT = K >> 5;
    load_tile(0);
    write_tile(0);
    __syncthreads();
    for (int t = 0; t < NT; ++t) {
        const int cur = t & 1;
        if (t + 1 < NT) load_tile((t + 1) * 32);
        bf16x8 af[4], bfr[4];
#pragma unroll
        for (int f = 0; f < 4; ++f) {
            af[f]  = *(const bf16x8*)&LA[cur][lg][wr * 64 + f * 16 + l15][0];
            bfr[f] = *(const bf16x8*)&LW[cur][lg][wc * 64 + f * 16 + l15][0];
        }
#pragma unroll
        for (int fm = 0; fm < 4; ++fm)
#pragma unroll
            for (int fn = 0; fn < 4; ++fn)
                acc[fm][fn] = __builtin_amdgcn_mfma_f32_16x16x32_bf16(af[fm], bfr[fn], acc[fm][fn], 0, 0, 0);
        if (t + 1 < NT) write_tile(cur ^ 1);
        __syncthreads();
    }

#pragma unroll
    for (int fm = 0; fm < 4; ++fm) {
        const int row = m0 + wr * 64 + fm * 16 + lg * 4;
#pragma unroll
        for (int fn = 0; fn < 4; ++fn) {
            const int coln = n0 + wc * 64 + fn * 16 + l15;
            const float bsv = bias[coln];
#pragma unroll
            for (int r = 0; r < 4; ++r) {
                const int gr = row + r;
                if (gr >= M) continue;
                float v = acc[fm][fn][r] + bsv;
                if (RELU) v = fmaxf(v, 0.f);
                if (OUT_BF16)
                    ((__hip_bfloat16*)Cv)[(size_t)gr * ldc + col0 + coln] = __float2bfloat16(v);
                else
                    ((float*)Cv)[(size_t)gr * ldc + col0 + coln] = v;
            }
        }
    }
}

// ---------------------------------------------------------------------------
// 64x64-tile GEMM (machine fill): 256 thr, 4 waves 2x2, per-wave 32x32.
// Grid (N/64) x ceil(M/64).
// ---------------------------------------------------------------------------
template<bool A_FP32, bool OUT_BF16>
__global__ __launch_bounds__(256)
void gemm64(const void* __restrict__ Av, const __hip_bfloat16* __restrict__ W,
            const float* __restrict__ bias, void* __restrict__ Cv,
            int M, int K, int ldc, int col0) {
    __shared__ __hip_bfloat16 LA[2][4][65][8];
    __shared__ __hip_bfloat16 LW[2][4][65][8];
    const int tid = threadIdx.x;
    const int lane = tid & 63, wave = tid >> 6;
    const int wr = wave >> 1, wc = wave & 1;
    const int m0 = blockIdx.y * 64, n0 = blockIdx.x * 64;
    const int l15 = lane & 15, lg = lane >> 4;
    const int srow = tid >> 2, koct = tid & 3;
    const int gm = m0 + srow;
    const bool okA = gm < M;
    const __hip_bfloat16* pAb = (const __hip_bfloat16*)Av + (size_t)(okA ? gm : 0) * K + koct * 8;
    const float* pAf = (const float*)Av + (size_t)(okA ? gm : 0) * K + koct * 8;
    const __hip_bfloat16* pW = W + (size_t)(n0 + srow) * K + koct * 8;

    bf16x8 aR, wR;
    float4 f0R, f1R;
    auto load_tile = [&](int k0) {
        if (A_FP32) {
            f0R = okA ? *(const float4*)(pAf + k0)     : make_float4(0.f, 0.f, 0.f, 0.f);
            f1R = okA ? *(const float4*)(pAf + k0 + 4) : make_float4(0.f, 0.f, 0.f, 0.f);
        } else {
            aR = okA ? *(const bf16x8*)(pAb + k0) : (bf16x8){0, 0, 0, 0, 0, 0, 0, 0};
        }
        wR = *(const bf16x8*)(pW + k0);
    };
    auto write_tile = [&](int buf) {
        bf16x8 v;
        if (A_FP32)
            v = (bf16x8){f2bs(f0R.x), f2bs(f0R.y), f2bs(f0R.z), f2bs(f0R.w),
                         f2bs(f1R.x), f2bs(f1R.y), f2bs(f1R.z), f2bs(f1R.w)};
        else
            v = aR;
        *(bf16x8*)&LA[buf][koct][srow][0] = v;
        *(bf16x8*)&LW[buf][koct][srow][0] = wR;
    };

    f32x4 acc[2][2];
#pragma unroll
    for (int i = 0; i < 2; ++i)
#pragma unroll
        for (int j = 0; j < 2; ++j) acc[i][j] = (f32x4){0.f, 0.f, 0.f, 0.f};

    const int NT = K >> 5;
    load_tile(0);
    write_tile(0);
    __syncthreads();
    for (int t = 0; t < NT; ++t) {
        const int cur = t & 1;
        if (t + 1 < NT) load_tile((t + 1) * 32);
        bf16x8 af[2], bfr[2];
#pragma unroll
        for (int f = 0; f < 2; ++f) {
            af[f]  = *(const bf16x8*)&LA[cur][lg][wr * 32 + f * 16 + l15][0];
            bfr[f] = *(const bf16x8*)&LW[cur][lg][wc * 32 + f * 16 + l15][0];
        }
#pragma unroll
        for (int fm = 0; fm < 2; ++fm)
#pragma unroll
            for (int fn = 0; fn < 2; ++fn)
                acc[fm][fn] = __builtin_amdgcn_mfma_f32_16x16x32_bf16(af[fm], bfr[fn], acc[fm][fn], 0, 0, 0);
        if (t + 1 < NT) write_tile(cur ^ 1);
        __syncthreads();
    }

#pragma unroll
    for (int fm = 0; fm < 2; ++fm) {
        const int row = m0 + wr * 32 + fm * 16 + lg * 4;
#pragma unroll
        for (int fn = 0; fn < 2; ++fn) {
            const int coln = n0 + wc * 32 + fn * 16 + l15;
            const float bsv = bias[coln];
#pragma unroll
            for (int r = 0; r < 4; ++r) {
                const int gr = row + r;
                if (gr >= M) continue;
                float v = acc[fm][fn][r] + bsv;
                if (OUT_BF16)
                    ((__hip_bfloat16*)Cv)[(size_t)gr * ldc + col0 + coln] = __float2bfloat16(v);
                else
                    ((float*)Cv)[(size_t)gr * ldc + col0 + coln] = v;
            }
        }
    }
}

// ---------------------------------------------------------------------------
// gemm64qa: fused offsets+attn-weights projection. A = Qb (bf16), W = packed
// [w_off (256 rows) | w_aw (128 rows)] contiguous, N = 384. Split epilogue:
// cols <256 -> Coff (fp32, ld 256); cols >=256 -> Caw (fp32, ld 128).
// ---------------------------------------------------------------------------
__global__ __launch_bounds__(256)
void gemm64qa(const __hip_bfloat16* __restrict__ Ab, const __hip_bfloat16* __restrict__ W,
              const float* __restrict__ boff, const float* __restrict__ baw,
              float* __restrict__ Coff, float* __restrict__ Caw, int M, int K) {
    __shared__ __hip_bfloat16 LA[2][4][65][8];
    __shared__ __hip_bfloat16 LW[2][4][65][8];
    const int tid = threadIdx.x;
    const int lane = tid & 63, wave = tid >> 6;
    const int wr = wave >> 1, wc = wave & 1;
    const int m0 = blockIdx.y * 64, n0 = blockIdx.x * 64;
    const int l15 = lane & 15, lg = lane >> 4;
    const int srow = tid >> 2, koct = tid & 3;
    const int gm = m0 + srow;
    const bool okA = gm < M;
    const __hip_bfloat16* pAb = Ab + (size_t)(okA ? gm : 0) * K + koct * 8;
    const __hip_bfloat16* pW = W + (size_t)(n0 + srow) * K + koct * 8;

    bf16x8 aR, wR;
    auto load_tile = [&](int k0) {
        aR = okA ? *(const bf16x8*)(pAb + k0) : (bf16x8){0, 0, 0, 0, 0, 0, 0, 0};
        wR = *(const bf16x8*)(pW + k0);
    };
    auto write_tile = [&](int buf) {
        *(bf16x8*)&LA[buf][koct][srow][0] = aR;
        *(bf16x8*)&LW[buf][koct][srow][0] = wR;
    };

    f32x4 acc[2][2];
#pragma unroll
    for (int i = 0; i < 2; ++i)
#pragma unroll
        for (int j = 0; j < 2; ++j) acc[i][j] = (f32x4){0.f, 0.f, 0.f, 0.f};

    const int NT = K >> 5;
    load_tile(0);
    write_tile(0);
    __syncthreads();
    for (int t = 0; t < NT; ++t) {
        const int cur = t & 1;
        if (t + 1 < NT) load_tile((t + 1) * 32);
        bf16x8 af[2], bfr[2];
#pragma unroll
        for (int f = 0; f < 2; ++f) {
            af[f]  = *(const bf16x8*)&LA[cur][lg][wr * 32 + f * 16 + l15][0];
            bfr[f] = *(const bf16x8*)&LW[cur][lg][wc * 32 + f * 16 + l15][0];
        }
#pragma unroll
        for (int fm = 0; fm < 2; ++fm)
#pragma unroll
            for (int fn = 0; fn < 2; ++fn)
                acc[fm][fn] = __builtin_amdgcn_mfma_f32_16x16x32_bf16(af[fm], bfr[fn], acc[fm][fn], 0, 0, 0);
        if (t + 1 < NT) write_tile(cur ^ 1);
        __syncthreads();
    }

#pragma unroll
    for (int fm = 0; fm < 2; ++fm) {
        const int row = m0 + wr * 32 + fm * 16 + lg * 4;
#pragma unroll
        for (int fn = 0; fn < 2; ++fn) {
            const int coln = n0 + wc * 32 + fn * 16 + l15;
#pragma unroll
            for (int r = 0; r < 4; ++r) {
                const int gr = row + r;
                if (gr >= M) continue;
                if (coln < 256) {
                    Coff[(size_t)gr * 256 + coln] = acc[fm][fn][r] + boff[coln];
                } else {
                    Caw[(size_t)gr * 128 + (coln - 256)] = acc[fm][fn][r] + baw[coln - 256];
                }
            }
        }
    }
}

// ---------------------------------------------------------------------------
// gemm64x: value projection (M=90024, N=256, fp32 A -> bf16 C).
// 5628 blocks + m204 bijective XCD-chunked swizzle (FETCH 45.6 MB measured).
// ---------------------------------------------------------------------------
__global__ __launch_bounds__(256)
void gemm64x(const float* __restrict__ Av, const __hip_bfloat16* __restrict__ W,
             const float* __restrict__ bias, __hip_bfloat16* __restrict__ Cv,
             int M, int K, int ldc) {
    const int nwg = gridDim.x;
    const int orig = blockIdx.x;
    const int xcd = orig & 7, loc = orig >> 3;
    const int q = nwg >> 3, r = nwg & 7;
    const int swz = (xcd < r ? xcd * (q + 1) : r * (q + 1) + (xcd - r) * q) + loc;
    const int m0 = (swz >> 2) * 64, n0 = (swz & 3) * 64;

    __shared__ __hip_bfloat16 LA[2][4][65][8];
    __shared__ __hip_bfloat16 LW[2][4][65][8];
    const int tid = threadIdx.x;
    const int lane = tid & 63, wave = tid >> 6;
    const int wr = wave >> 1, wc = wave & 1;
    const int l15 = lane & 15, lg = lane >> 4;
    const int srow = tid >> 2, koct = tid & 3;
    const int gm = m0 + srow;
    const bool okA = gm < M;
    const float* pAf = Av + (size_t)(okA ? gm : 0) * K + koct * 8;
    const __hip_bfloat16* pW = W + (size_t)(n0 + srow) * K + koct * 8;

    bf16x8 wR;
    float4 f0R, f1R;
    auto load_tile = [&](int k0) {
        f0R = okA ? *(const float4*)(pAf + k0)     : make_float4(0.f, 0.f, 0.f, 0.f);
        f1R = okA ? *(const float4*)(pAf + k0 + 4) : make_float4(0.f, 0.f, 0.f, 0.f);
        wR = *(const bf16x8*)(pW + k0);
    };
    auto write_tile = [&](int buf) {
        *(bf16x8*)&LA[buf][koct][srow][0] =
            (bf16x8){f2bs(f0R.x), f2bs(f0R.y), f2bs(f0R.z), f2bs(f0R.w),
                     f2bs(f1R.x), f2bs(f1R.y), f2bs(f1R.z), f2bs(f1R.w)};
        *(bf16x8*)&LW[buf][koct][srow][0] = wR;
    };

    f32x4 acc[2][2];
#pragma unroll
    for (int i = 0; i < 2; ++i)
#pragma unroll
        for (int j = 0; j < 2; ++j) acc[i][j] = (f32x4){0.f, 0.f, 0.f, 0.f};

    const int NT = K >> 5;
    load_tile(0);
    write_tile(0);
    __syncthreads();
    for (int t = 0; t < NT; ++t) {
        const int cur = t & 1;
        if (t + 1 < NT) load_tile((t + 1) * 32);
        bf16x8 af[2], bfr[2];
#pragma unroll
        for (int f = 0; f < 2; ++f) {
            af[f]  = *(const bf16x8*)&LA[cur][lg][wr * 32 + f * 16 + l15][0];
            bfr[f] = *(const bf16x8*)&LW[cur][lg][wc * 32 + f * 16 + l15][0];
        }
#pragma unroll
        for (int fm = 0; fm < 2; ++fm)
#pragma unroll
            for (int fn = 0; fn < 2; ++fn)
                acc[fm][fn] = __builtin_amdgcn_mfma_f32_16x16x32_bf16(af[fm], bfr[fn], acc[fm][fn], 0, 0, 0);
        if (t + 1 < NT) write_tile(cur ^ 1);
        __syncthreads();
    }

#pragma unroll
    for (int fm = 0; fm < 2; ++fm) {
        const int row = m0 + wr * 32 + fm * 16 + lg * 4;
#pragma unroll
        for (int fn = 0; fn < 2; ++fn) {
            const int coln = n0 + wc * 32 + fn * 16 + l15;
            const float bsv = bias[coln];
#pragma unroll
            for (int r = 0; r < 4; ++r) {
                const int gr = row + r;
                if (gr >= M) continue;
                Cv[(size_t)gr * ldc + coln] = __float2bfloat16(acc[fm][fn][r] + bsv);
            }
        }
    }
}

// ---------------------------------------------------------------------------
// Fused weight conversion fp32 -> bf16 into one packed buffer.
// ---------------------------------------------------------------------------
__global__ void cvt_weights(const float* w0, const float* w1, const float* w2,
                            const float* w3, const float* w4, const float* w5,
                            const float* w6, const float* w7, const float* w8,
                            const float* w9, __hip_bfloat16* dst) {
    int idx = blockIdx.x * 256 + threadIdx.x;
    float v;
    if      (idx <  196608) v = w0[idx];
    else if (idx <  262144) v = w1[idx -  196608];
    else if (idx <  458752) v = w2[idx -  262144];
    else if (idx <  524288) v = w3[idx -  458752];
    else if (idx <  589824) v = w4[idx -  524288];
    else if (idx <  622592) v = w5[idx -  589824];
    else if (idx <  688128) v = w6[idx -  622592];
    else if (idx <  753664) v = w7[idx -  688128];
    else if (idx < 1015808) v = w8[idx -  753664];
    else                    v = w9[idx - 1015808];
    dst[idx] = __float2bfloat16(v);
}

// ---------------------------------------------------------------------------
// Row gather (+optional add) -> contiguous bf16 (t, 256) buffer.
// ---------------------------------------------------------------------------
__global__ void gather_rows_b(const float* __restrict__ src, const float* __restrict__ add,
                              __hip_bfloat16* __restrict__ dst, int mode) {
    int t = blockIdx.x, c = threadIdx.x;
    int r;
    if (mode == 0) r = t;
    else if (mode == 1) { int m = t / 100, q = t % 100; r = q * 136 + m; }
    else { int b = t / 1700, jj = t % 1700; int q = jj / 17, p = jj % 17; r = q * 136 + b * 17 + p; }
    float v = src[(size_t)r * 256 + c];
    if (add) v += add[(size_t)r * 256 + c];
    dst[(size_t)t * 256 + c] = __float2bfloat16(v);
}

// ---------------------------------------------------------------------------
// MHA S=17 (group attention). qkv BF16 rows t*768 (Q|K|V). block=(group, head)
// ---------------------------------------------------------------------------
__global__ void attn17(const __hip_bfloat16* __restrict__ qkv, __hip_bfloat16* __restrict__ out) {
    const int g = blockIdx.x, h = blockIdx.y;
    __shared__ float q[17][32], k[17][32], v[17][32], s[17][18];
    const int tid = threadIdx.x;  // 256
    for (int idx = tid; idx < 17 * 32; idx += 256) {
        int i = idx >> 5, d = idx & 31;
        size_t row = (size_t)(g * 17 + i) * 768 + h * 32 + d;
        q[i][d] = bs2f(*(const short*)&qkv[row]);
        k[i][d] = bs2f(*(const short*)&qkv[row + 256]);
        v[i][d] = bs2f(*(const short*)&qkv[row + 512]);
    }
    __syncthreads();
    for (int idx = tid; idx < 17 * 17; idx += 256) {
        int i = idx / 17, j = idx % 17;
        float acc = 0.f;
#pragma unroll
        for (int d = 0; d < 32; ++d) acc += q[i][d] * k[j][d];
        s[i][j] = acc * 0.17677669529663688f;
    }
    __syncthreads();
    if (tid < 17) {
        float m = -1e30f;
        for (int j = 0; j < 17; ++j) m = fmaxf(m, s[tid][j]);
        float sum = 0.f;
        for (int j = 0; j < 17; ++j) { float e = __expf(s[tid][j] - m); s[tid][j] = e; sum += e; }
        float inv = 1.f / sum;
        for (int j = 0; j < 17; ++j) s[tid][j] *= inv;
    }
    __syncthreads();
    for (int idx = tid; idx < 17 * 32; idx += 256) {
        int i = idx >> 5, d = idx & 31;
        float acc = 0.f;
        for (int j = 0; j < 17; ++j) acc += s[i][j] * v[j][d];
        out[(size_t)(g * 17 + i) * 256 + h * 32 + d] = __float2bfloat16(acc);
    }
}

// ---------------------------------------------------------------------------
// MHA S=100 v2: MFMA flash per (group, head). 128 thr = 2 waves. qkv BF16.
// ---------------------------------------------------------------------------
__global__ __launch_bounds__(128)
void attn100(const __hip_bfloat16* __restrict__ qkv, __hip_bfloat16* __restrict__ out) {
    const int g = blockIdx.x, h = blockIdx.y;
    __shared__ __hip_bfloat16 Vt[32][136];
    __shared__ __hip_bfloat16 Pl[2][16][136];
    const int tid = threadIdx.x;
    const int wave = tid >> 6, lane = tid & 63;
    const int l15 = lane & 15, lg = lane >> 4;

    for (int idx = tid; idx < 3200; idx += 128) {
        int j = idx >> 5, d = idx & 31;
        Vt[d][j] = qkv[(size_t)(g * 100 + j) * 768 + 512 + h * 32 + d];
    }
    for (int idx = tid; idx < 32 * 28; idx += 128) {
        int d = idx & 31, jz = 100 + (idx >> 5);
        Vt[d][jz] = __float2bfloat16(0.f);
    }
    __syncthreads();

    const int rt0 = wave ? 4 : 0, rt1 = wave ? 7 : 4;
    for (int rt = rt0; rt < rt1; ++rt) {
        const int rowbase = rt * 16;
        int qr = rowbase + l15; if (qr > 99) qr = 99;
        bf16x8 aq = *(const bf16x8*)(qkv + (size_t)(g * 100 + qr) * 768 + h * 32 + lg * 8);
        f32x4 s[7];
#pragma unroll
        for (int jt = 0; jt < 7; ++jt) {
            int jr = jt * 16 + l15; if (jr > 99) jr = 99;
            bf16x8 bk = *(const bf16x8*)(qkv + (size_t)(g * 100 + jr) * 768 + 256 + h * 32 + lg * 8);
            s[jt] = __builtin_amdgcn_mfma_f32_16x16x32_bf16(aq, bk, (f32x4){0.f, 0.f, 0.f, 0.f}, 0, 0, 0);
        }
        float mr[4] = {-1e30f, -1e30f, -1e30f, -1e30f};
#pragma unroll
        for (int jt = 0; jt < 7; ++jt) {
            const bool valid = (jt * 16 + l15) < 100;
#pragma unroll
            for (int r = 0; r < 4; ++r) {
                float v = valid ? s[jt][r] * 0.17677669529663688f : -1e30f;
                s[jt][r] = v;
                mr[r] = fmaxf(mr[r], v);
            }
        }
#pragma unroll
        for (int r = 0; r < 4; ++r) {
            mr[r] = fmaxf(mr[r], __shfl_xor(mr[r], 1));
            mr[r] = fmaxf(mr[r], __shfl_xor(mr[r], 2));
            mr[r] = fmaxf(mr[r], __shfl_xor(mr[r], 4));
            mr[r] = fmaxf(mr[r], __shfl_xor(mr[r], 8));
        }
        float lr[4] = {0.f, 0.f, 0.f, 0.f};
#pragma unroll
        for (int jt = 0; jt < 7; ++jt)
#pragma unroll
            for (int r = 0; r < 4; ++r) {
                float e = __expf(s[jt][r] - mr[r]);
                s[jt][r] = e;
                lr[r] += e;
            }
#pragma unroll
        for (int r = 0; r < 4; ++r) {
            lr[r] += __shfl_xor(lr[r], 1);
            lr[r] += __shfl_xor(lr[r], 2);
            lr[r] += __shfl_xor(lr[r], 4);
            lr[r] += __shfl_xor(lr[r], 8);
        }
#pragma unroll
        for (int jt = 0; jt < 7; ++jt)
#pragma unroll
            for (int r = 0; r < 4; ++r)
                Pl[wave][lg * 4 + r][jt * 16 + l15] = __float2bfloat16(s[jt][r]);
#pragma unroll
        for (int r = 0; r < 4; ++r)
            Pl[wave][lg * 4 + r][112 + l15] = __float2bfloat16(0.f);

        f32x4 o0 = (f32x4){0.f, 0.f, 0.f, 0.f};
        f32x4 o1 = (f32x4){0.f, 0.f, 0.f, 0.f};
#pragma unroll
        for (int c = 0; c < 4; ++c) {
            bf16x8 pa = *(const bf16x8*)&Pl[wave][l15][c * 32 + lg * 8];
            bf16x8 v0 = *(const bf16x8*)&Vt[l15][c * 32 + lg * 8];
            bf16x8 v1 = *(const bf16x8*)&Vt[16 + l15][c * 32 + lg * 8];
            o0 = __builtin_amdgcn_mfma_f32_16x16x32_bf16(pa, v0, o0, 0, 0, 0);
            o1 = __builtin_amdgcn_mfma_f32_16x16x32_bf16(pa, v1, o1, 0, 0, 0);
        }
#pragma unroll
        for (int r = 0; r < 4; ++r) {
            int row = rowbase + lg * 4 + r;
            if (row < 100) {
                float inv = 1.f / lr[r];
                __hip_bfloat16* op = out + (size_t)(g * 100 + row) * 256 + h * 32;
                op[l15]      = __float2bfloat16(o0[r] * inv);
                op[16 + l15] = __float2bfloat16(o1[r] * inv);
            }
        }
    }
}

// ---------------------------------------------------------------------------
// Deformable sampling: bf16 value input. block = 4 tokens, 256 threads.
// Batch-XCD affinity: block i -> XCD i%8 (HW round-robin) handles batch i%8
// tokens only, so each XCD's L2 streams a single batch's 5.76 MB value
// slice instead of all 8 (cuts cross-XCD HBM re-fetch). Bijective:
// t0 = (i&7)*1700 + (i>>3)*4, i in [0,3400).
// ---------------------------------------------------------------------------
#define TPB 4
__global__ __launch_bounds__(256)
void deform_sample(const __hip_bfloat16* __restrict__ value, const float* __restrict__ off,
                   const float* __restrict__ aw, const float* __restrict__ ref,
                   __hip_bfloat16* __restrict__ out) {
    const int bi = blockIdx.x;
    const int t0 = (bi & 7) * 1700 + (bi >> 3) * TPB;
    const int tid = threadIdx.x;
    __shared__ float raw[TPB][128];
    __shared__ float wgt[TPB][128];
    __shared__ int   cidx[TPB][128][4];
    __shared__ float cw[TPB][128][4];

    for (int idx = tid; idx < TPB * 128; idx += 256) {
        int tk = idx >> 7, i = idx & 127;
        raw[tk][i] = aw[(size_t)(t0 + tk) * 128 + i];
    }
    __syncthreads();
    if (tid < TPB * 8) {
        int tk = tid >> 3, h = tid & 7;
        float m = -1e30f;
        for (int i = 0; i < 16; ++i) m = fmaxf(m, raw[tk][h * 16 + i]);
        float sum = 0.f;
        float e[16];
        for (int i = 0; i < 16; ++i) { e[i] = __expf(raw[tk][h * 16 + i] - m); sum += e[i]; }
        float inv = 1.f / sum;
        for (int i = 0; i < 16; ++i) wgt[tk][h * 16 + i] = e[i] * inv;
    }
    __syncthreads();

    const int Hs[4] = {92, 46, 23, 12};
    const int Sts[4] = {0, 8464, 10580, 11109};
    for (int s = tid; s < TPB * 128; s += 256) {
        int tk = s >> 7, sid = s & 127;
        int t = t0 + tk;
        int b = t / 1700, jj = t % 1700;
        int q = jj / 17, p = jj % 17;
        int l = (sid >> 2) & 3;
        int HW = Hs[l];
        float HWf = (float)HW;
        const float* refp = ref + (size_t)((q * 8 + b) * 17 + p) * 8;
        float rx = refp[l * 2], ry = refp[l * 2 + 1];
        float ox = off[(size_t)t * 256 + sid * 2];
        float oy = off[(size_t)t * 256 + sid * 2 + 1];
        float x = (rx + ox / HWf) * HWf - 0.5f;
        float y = (ry + oy / HWf) * HWf - 0.5f;
        float x0f = floorf(x), y0f = floorf(y);
        float wx = x - x0f, wy = y - y0f;
        int xi = (int)x0f, yi = (int)y0f;
        float wg = wgt[tk][sid];
#pragma unroll
        for (int c = 0; c < 4; ++c) {
            int cy = c >> 1, cx = c & 1;
            int yy = yi + cy, xx = xi + cx;
            bool ok = (xx >= 0) && (xx < HW) && (yy >= 0) && (yy < HW);
            int yc = min(max(yy, 0), HW - 1);
            int xc = min(max(xx, 0), HW - 1);
            cidx[tk][sid][c] = Sts[l] + yc * HW + xc;
            float w = (cy ? wy : 1.f - wy) * (cx ? wx : 1.f - wx);
            cw[tk][sid][c] = ok ? wg * w : 0.f;
        }
    }
    __syncthreads();

    const int tk = tid >> 6, lane = tid & 63;
    const int h = lane >> 3, d4 = (lane & 7) * 4;
    const int t = t0 + tk;
    const int b = t / 1700;
    const __hip_bfloat16* vb = value + (size_t)b * LENIN * 256 + h * 32 + d4;
    float4 acc = make_float4(0.f, 0.f, 0.f, 0.f);
    for (int s16 = 0; s16 < 16; ++s16) {
        int sid = h * 16 + s16;
#pragma unroll
        for (int c = 0; c < 4; ++c) {
            int idx = cidx[tk][sid][c];
            float w = cw[tk][sid][c];
            bf16x4s v = *(const bf16x4s*)(vb + (size_t)idx * 256);
            acc.x += w * bs2f(v.x); acc.y += w * bs2f(v.y);
            acc.z += w * bs2f(v.z); acc.w += w * bs2f(v.w);
        }
    }
    __hip_bfloat16* op = out + (size_t)t * 256 + h * 32 + d4;
    op[0] = __float2bfloat16(acc.x);
    op[1] = __float2bfloat16(acc.y);
    op[2] = __float2bfloat16(acc.z);
    op[3] = __float2bfloat16(acc.w);
}

// ---------------------------------------------------------------------------
// Residual + LayerNorm over D=256: one WAVE per row, shuffle reduce, no LDS.
// ---------------------------------------------------------------------------
__global__ __launch_bounds__(256)
void res_ln(const float* __restrict__ res, const float* __restrict__ proj,
            const float* __restrict__ g, const float* __restrict__ be,
            float* __restrict__ out, __hip_bfloat16* __restrict__ outb, int mode) {
    const int wave = threadIdx.x >> 6, lane = threadIdx.x & 63;
    const int r = blockIdx.x * 4 + wave;
    int t;
    if (mode == 0) t = r;
    else if (mode == 1) { int q = r / 136, m = r % 136; t = m * 100 + q; }
    else { int q = r / 136, rem = r % 136; int b = rem / 17, p = rem % 17; t = b * 1700 + q * 17 + p; }
    const int c4 = lane * 4;
    float4 a = *(const float4*)&res[(size_t)r * 256 + c4];
    float4 p = *(const float4*)&proj[(size_t)t * 256 + c4];
    float v[4] = {a.x + p.x, a.y + p.y, a.z + p.z, a.w + p.w};
    float s = v[0] + v[1] + v[2] + v[3];
#pragma unroll
    for (int off = 32; off > 0; off >>= 1) s += __shfl_xor(s, off);
    float mean = s * (1.f / 256.f);
    float d[4], ss = 0.f;
#pragma unroll
    for (int i = 0; i < 4; ++i) { d[i] = v[i] - mean; ss += d[i] * d[i]; }
#pragma unroll
    for (int off = 32; off > 0; off >>= 1) ss += __shfl_xor(ss, off);
    float rs = rsqrtf(ss * (1.f / 256.f) + 1e-5f);
    float4 gv = *(const float4*)&g[c4];
    float4 bv = *(const float4*)&be[c4];
    float o0 = d[0] * rs * gv.x + bv.x;
    float o1 = d[1] * rs * gv.y + bv.y;
    float o2 = d[2] * rs * gv.z + bv.z;
    float o3 = d[3] * rs * gv.w + bv.w;
    *(float4*)&out[(size_t)r * 256 + c4] = make_float4(o0, o1, o2, o3);
    if (outb) {
        bf16x4s ob = {f2bs(o0), f2bs(o1), f2bs(o2), f2bs(o3)};
        *(bf16x4s*)&outb[(size_t)r * 256 + c4] = ob;
    }
}

// ---------------------------------------------------------------------------
extern "C" void kernel_launch(void* const* d_in, const int* in_sizes, int n_in,
                              void* d_out, int out_size, void* d_ws, size_t ws_size,
                              hipStream_t stream) {
    const float* tgt    = (const float*)d_in[0];
    const float* qpos   = (const float*)d_in[1];
    const float* ref    = (const float*)d_in[2];
    const float* memory = (const float*)d_in[3];
    const float* w_in_w = (const float*)d_in[4];
    const float* b_in_w = (const float*)d_in[5];
    const float* w_out_w= (const float*)d_in[6];
    const float* b_out_w= (const float*)d_in[7];
    const float* w_in_a = (const float*)d_in[8];
    const float* b_in_a = (const float*)d_in[9];
    const float* w_out_a= (const float*)d_in[10];
    const float* b_out_a= (const float*)d_in[11];
    const float* w_off  = (const float*)d_in[12];
    const float* b_off  = (const float*)d_in[13];
    const float* w_aw   = (const float*)d_in[14];
    const float* b_aw   = (const float*)d_in[15];
    const float* w_val  = (const float*)d_in[16];
    const float* b_val  = (const float*)d_in[17];
    const float* w_oc   = (const float*)d_in[18];
    const float* b_oc   = (const float*)d_in[19];
    const float* g_w    = (const float*)d_in[20];
    const float* be_w   = (const float*)d_in[21];
    const float* g_a    = (const float*)d_in[22];
    const float* be_a   = (const float*)d_in[23];
    const float* g1     = (const float*)d_in[24];
    const float* be1    = (const float*)d_in[25];
    const float* g2     = (const float*)d_in[26];
    const float* be2    = (const float*)d_in[27];
    const float* w1     = (const float*)d_in[28];
    const float* b1     = (const float*)d_in[29];
    const float* w2     = (const float*)d_in[30];
    const float* b2     = (const float*)d_in[31];

    float* X  = (float*)d_out;
    float* ws = (float*)d_ws;
    float* R1 = ws;
    float* R2 = R1 + (size_t)MTOK * 256;
    float* R3 = R2 + (size_t)NTOK * 256;
    float* R6 = R3 + (size_t)NTOK * 128;
    float* QBF= R6 + (size_t)NTOK * 128;
    float* WBF= QBF+ (size_t)NTOK * 128;

    __hip_bfloat16* R1b = (__hip_bfloat16*)R1;
    __hip_bfloat16* R3b = (__hip_bfloat16*)R3;
    __hip_bfloat16* Qb  = (__hip_bfloat16*)QBF;
    __hip_bfloat16* Wb  = (__hip_bfloat16*)WBF;
    __hip_bfloat16* Hb  = (__hip_bfloat16*)R1;
    __hip_bfloat16* Vb  = (__hip_bfloat16*)R1;

    __hip_bfloat16* w_in_w_b  = Wb;
    __hip_bfloat16* w_out_w_b = Wb +  196608;
    __hip_bfloat16* w_in_a_b  = Wb +  262144;
    __hip_bfloat16* w_out_a_b = Wb +  458752;
    __hip_bfloat16* w_off_b   = Wb +  524288;
    __hip_bfloat16* w_aw_b    = Wb +  589824;
    __hip_bfloat16* w_val_b   = Wb +  622592;
    __hip_bfloat16* w_oc_b    = Wb +  688128;
    __hip_bfloat16* w1_b      = Wb +  753664;
    __hip_bfloat16* w2_b      = Wb + 1015808;

    cvt_weights<<<4992, 256, 0, stream>>>(w_in_w, w_out_w, w_in_a, w_out_a, w_off,
                                          w_aw, w_val, w_oc, w1, w2, Wb);

    const int MY64 = (NTOK + 63) / 64;   // 213

    // ---- Phase 1: group self-attention (S=17), qkv bf16, all-64-tile ----
    gather_rows_b<<<NTOK, 256, 0, stream>>>(tgt, qpos, Qb, 0);
    gemm64<false, true><<<dim3(8, MY64), 256, 0, stream>>>(
        Qb, w_in_w_b, b_in_w, R1b, NTOK, 256, 768, 0);
    gemm64<true, true><<<dim3(4, MY64), 256, 0, stream>>>(
        tgt, w_in_w_b + 512 * 256, b_in_w + 512, R1b, NTOK, 256, 768, 512);
    attn17<<<dim3(800, 8), 256, 0, stream>>>(R1b, R3b);
    gemm64<false, false><<<dim3(4, MY64), 256, 0, stream>>>(
        R3b, w_out_w_b, b_out_w, R2, NTOK, 256, 256, 0);
    res_ln<<<NTOK / 4, 256, 0, stream>>>(tgt, R2, g_w, be_w, X, nullptr, 0);

    // ---- Phase 2: query self-attention (S=100), qkv bf16, all-64-tile ----
    gather_rows_b<<<NTOK, 256, 0, stream>>>(X, nullptr, Qb, 1);
    gemm64<false, true><<<dim3(12, MY64), 256, 0, stream>>>(
        Qb, w_in_a_b, b_in_a, R1b, NTOK, 256, 768, 0);
    attn100<<<dim3(136, 8), 128, 0, stream>>>(R1b, R3b);
    gemm64<false, false><<<dim3(4, MY64), 256, 0, stream>>>(
        R3b, w_out_a_b, b_out_a, R2, NTOK, 256, 256, 0);
    res_ln<<<NTOK / 4, 256, 0, stream>>>(X, R2, g_a, be_a, X, nullptr, 1);

    // ---- Phase 3: deformable attention ----
    gemm64x<<<4 * ((MTOK + 63) / 64), 256, 0, stream>>>(
        memory, w_val_b, b_val, Vb, MTOK, 256, 256);
    gather_rows_b<<<NTOK, 256, 0, stream>>>(X, qpos, Qb, 2);
    gemm64qa<<<dim3(6, MY64), 256, 0, stream>>>(
        Qb, w_off_b, b_off, b_aw, R2, R6, NTOK, 256);   // off+aw fused (W rows contiguous)
    deform_sample<<<NTOK / TPB, 256, 0, stream>>>(Vb, R2, R6, ref, R3b);
    gemm64<false, false><<<dim3(4, MY64), 256, 0, stream>>>(
        R3b, w_oc_b, b_oc, R2, NTOK, 256, 256, 0);
    res_ln<<<NTOK / 4, 256, 0, stream>>>(X, R2, g1, be1, X, Qb, 2);

    // ---- Phase 4: FFN ----
    gemm_mfma<true, true, false><<<dim3(8, (NTOK + 127) / 128), 256, 0, stream>>>(
        Qb, w1_b, b1, Hb, NTOK, 1024, 256, 1024, 0);
    gemm64<false, false><<<dim3(4, MY64), 256, 0, stream>>>(
        (const __hip_bfloat16*)Hb, w2_b, b2, R2, NTOK, 1024, 256, 0);
    res_ln<<<NTOK / 4, 256, 0, stream>>>(X, R2, g2, be2, X, nullptr, 0);
}